// Round 6
// baseline (4326.369 us; speedup 1.0000x reference)
//
#include <hip/hip_runtime.h>
#include <math.h>

#define D_MODEL 1024
#define D_STATE 32
#define D_CONV  4
#define D_INNER 2048
#define DT_RANK 64
#define BATCH   4
#define SEQ     2048
#define NTOK    (BATCH*SEQ)            // 8192 rows
#define DBC_N   (DT_RANK + 2*D_STATE)  // 128

typedef unsigned short u16;

__device__ __forceinline__ float bf2f(u16 u){
  return __uint_as_float(((unsigned)u) << 16);
}
__device__ __forceinline__ u16 f2bf(float f){   // round-to-nearest-even
  unsigned u = __float_as_uint(f);
  return (u16)((u + 0x7fffu + ((u >> 16) & 1u)) >> 16);
}
__device__ __forceinline__ float sigmoidf_(float x){ return 1.f/(1.f+__expf(-x)); }

// ---------------------------------------------------------------------------
// f32 tiled GEMM: C[M,N] = A[M,K] @ B[K,N]  (row-major, runtime ld)
// CBF: true -> store bf16 (u16), false -> store f32.
// Requires: BM*BK == BN*BK == 1024 == 4 * blockDim (256 thr * float4)
// ---------------------------------------------------------------------------
template<int BM,int BN,int BK,int TM,int TN,bool CBF>
__global__ __launch_bounds__((BM/TM)*(BN/TN))
void sgemm(int K,
           const float* __restrict__ A,int lda,
           const float* __restrict__ B,int ldb,
           void* __restrict__ Cv,int ldc)
{
  __shared__ float As[BK][BM];
  __shared__ float Bs[BK][BN];
  const int tid  = threadIdx.x;
  const int brow = blockIdx.y, bcol = blockIdx.x;
  const int tcol = tid % (BN/TN);
  const int trow = tid / (BN/TN);

  const float* Ag = A + (size_t)brow*BM*lda;
  const float* Bg = B + (size_t)bcol*BN;

  // A-tile load map: one float4 per thread along K
  const int arow = tid / (BK/4);
  const int acol = (tid % (BK/4))*4;
  // B-tile load map: one float4 per thread along N
  const int brw  = tid / (BN/4);
  const int bcv  = (tid % (BN/4))*4;

  float acc[TM][TN] = {};

  for (int k0=0; k0<K; k0+=BK){
    float4 av = *(const float4*)(Ag + (size_t)arow*lda + k0 + acol);
    float4 bv = *(const float4*)(Bg + (size_t)(k0+brw)*ldb + bcv);
    __syncthreads();
    As[acol+0][arow]=av.x; As[acol+1][arow]=av.y;
    As[acol+2][arow]=av.z; As[acol+3][arow]=av.w;
    *(float4*)&Bs[brw][bcv] = bv;
    __syncthreads();
    #pragma unroll
    for (int kk=0;kk<BK;kk++){
      float ra[TM], rb[TN];
      #pragma unroll
      for (int m=0;m<TM;m++) ra[m]=As[kk][trow*TM+m];
      #pragma unroll
      for (int n=0;n<TN;n++) rb[n]=Bs[kk][tcol*TN+n];
      #pragma unroll
      for (int m=0;m<TM;m++)
        #pragma unroll
        for (int n=0;n<TN;n++)
          acc[m][n] += ra[m]*rb[n];
    }
  }

  #pragma unroll
  for (int m=0;m<TM;m++){
    int row = brow*BM + trow*TM + m;
    #pragma unroll
    for (int n=0;n<TN;n++){
      int col = bcol*BN + tcol*TN + n;
      if (CBF) ((u16*) Cv)[(size_t)row*ldc + col] = f2bf(acc[m][n]);
      else     ((float*)Cv)[(size_t)row*ldc + col] = acc[m][n];
    }
  }
}

// ---------------------------------------------------------------------------
// Depthwise causal conv (K=4) + bias + SiLU. xi_raw (f32, ld 2048) -> xi_post.
// ---------------------------------------------------------------------------
__global__ __launch_bounds__(256)
void conv_silu_kernel(const float* __restrict__ xi_raw,
                      const float* __restrict__ conv_w,
                      const float* __restrict__ conv_b,
                      float* __restrict__ xi_post)
{
  size_t idx = (size_t)blockIdx.x*256 + threadIdx.x;   // over NTOK*D_INNER
  int d = (int)(idx % D_INNER);
  size_t bt = idx / D_INNER;
  int t = (int)(bt % SEQ);
  size_t b = bt / SEQ;
  const float* xi = xi_raw + b*(size_t)SEQ*D_INNER;
  float accv = conv_b[d];
  #pragma unroll
  for (int k=0;k<D_CONV;k++){
    int tt = t + k - (D_CONV-1);
    if (tt >= 0) accv += xi[(size_t)tt*D_INNER + d] * conv_w[d*D_CONV + k];
  }
  xi_post[idx] = accv * sigmoidf_(accv);
}

// ---------------------------------------------------------------------------
// Selective scan with FUSED dt_proj + softplus.
// 32 lanes per (b,d) channel; 8 channels per 256-thr block.
// Per step: delta = softplus(dt[0:64] . dtW[:,d] + dtb[d])  (butterfly reduce)
//           h = exp(delta*A)*h + (delta*u)*B ; y = sum_s h*C
//           y_out = (y + u*D) * silu(z)       (z is bf16)
// ---------------------------------------------------------------------------
__global__ __launch_bounds__(256)
void scan_kernel(const float* __restrict__ dbc,     // (NTOK, 128) f32
                 const float* __restrict__ u,       // xi_post (NTOK, D_INNER) f32
                 const u16*   __restrict__ z,       // (NTOK, D_INNER) bf16
                 float* __restrict__ y,             // (NTOK, D_INNER) f32
                 const float* __restrict__ dtW,     // (DT_RANK, D_INNER)
                 const float* __restrict__ dtb,     // (D_INNER,)
                 const float* __restrict__ A_log,   // (D_INNER, 32)
                 const float* __restrict__ Dp)      // (D_INNER,)
{
  const int b    = blockIdx.x >> 8;          // 256 blocks per batch
  const int dblk = blockIdx.x & 255;
  const int c    = threadIdx.x >> 5;         // channel within block, 0..7
  const int s    = threadIdx.x & 31;         // state / reduce-lane index
  const int d    = dblk*8 + c;

  const float As = -__expf(A_log[d*D_STATE + s]);
  const float Dd = Dp[d];
  const float W0 = dtW[(size_t)s*D_INNER + d];        // dt_proj rows s, s+32
  const float W1 = dtW[(size_t)(s+32)*D_INNER + d];
  const float bd = dtb[d];

  const float* dbc_b = dbc + (size_t)b*SEQ*DBC_N;
  const float* u_bd  = u + (size_t)b*SEQ*D_INNER + d;
  const u16*   z_bd  = z + (size_t)b*SEQ*D_INNER + d;
  float*       y_bd  = y + (size_t)b*SEQ*D_INNER + d;

  float h = 0.f;
  for (int t=0; t<SEQ; ++t){
    const float* row = dbc_b + (size_t)t*DBC_N;
    float dt0 = row[s];
    float dt1 = row[32+s];
    float Bs  = row[64+s];
    float Cs  = row[96+s];
    float uu  = u_bd[(size_t)t*D_INNER];

    // delta = softplus(dt . W + b), butterfly so all lanes get it
    float pd = dt0*W0 + dt1*W1;
    #pragma unroll
    for (int off=16; off; off>>=1) pd += __shfl_xor(pd, off, 32);
    float v  = pd + bd;
    float dl = (v > 20.f) ? v : log1pf(__expf(v));

    h = __expf(dl*As)*h + (dl*uu)*Bs;
    float yv = h*Cs;
    #pragma unroll
    for (int off=16; off; off>>=1) yv += __shfl_xor(yv, off, 32);
    if (s == 0){
      float zz = bf2f(z_bd[(size_t)t*D_INNER]);
      y_bd[(size_t)t*D_INNER] = (yv + uu*Dd) * (zz * sigmoidf_(zz));
    }
  }
}

// ---------------------------------------------------------------------------
// LayerNorm over last dim (1024): read f32 pre-LN, write *** f32 *** output.
// ---------------------------------------------------------------------------
__global__ __launch_bounds__(256)
void ln_kernel(const float* __restrict__ in,
               float* __restrict__ out,
               const float* __restrict__ gamma,
               const float* __restrict__ beta)
{
  const int row = blockIdx.x;
  const float* p = in + (size_t)row*D_MODEL;
  float* q = out + (size_t)row*D_MODEL;
  float v[4]; float s=0.f, ss=0.f;
  #pragma unroll
  for (int i=0;i<4;i++){
    float x = p[i*256 + threadIdx.x];
    v[i]=x; s+=x; ss+=x*x;
  }
  #pragma unroll
  for (int off=32; off; off>>=1){
    s  += __shfl_xor(s,  off, 64);
    ss += __shfl_xor(ss, off, 64);
  }
  __shared__ float sw[4], ssw[4];
  const int wid = threadIdx.x >> 6;
  if ((threadIdx.x & 63) == 0){ sw[wid]=s; ssw[wid]=ss; }
  __syncthreads();
  s  = sw[0]+sw[1]+sw[2]+sw[3];
  ss = ssw[0]+ssw[1]+ssw[2]+ssw[3];
  const float mu  = s * (1.f/D_MODEL);
  const float var = ss * (1.f/D_MODEL) - mu*mu;
  const float inv = rsqrtf(var + 1e-5f);
  #pragma unroll
  for (int i=0;i<4;i++){
    int col = i*256 + threadIdx.x;
    q[col] = (v[i]-mu)*inv*gamma[col] + beta[col];
  }
}

// ---------------------------------------------------------------------------
extern "C" void kernel_launch(void* const* d_in, const int* in_sizes, int n_in,
                              void* d_out, int out_size, void* d_ws, size_t ws_size,
                              hipStream_t stream)
{
  const float* x          = (const float*)d_in[0];   // (4,2048,1024) f32
  const float* in_proj_w  = (const float*)d_in[1];   // (1024,4096)
  const float* conv_w     = (const float*)d_in[2];   // (2048,4)
  const float* conv_b     = (const float*)d_in[3];   // (2048,)
  const float* x_proj_w   = (const float*)d_in[4];   // (2048,128)
  const float* dt_proj_w  = (const float*)d_in[5];   // (64,2048)
  const float* dt_proj_b  = (const float*)d_in[6];   // (2048,)
  const float* A_log      = (const float*)d_in[7];   // (2048,32)
  const float* Dp         = (const float*)d_in[8];   // (2048,)
  const float* out_proj_w = (const float*)d_in[9];   // (2048,1024)
  const float* ln_gamma   = (const float*)d_in[10];  // (1024,)
  const float* ln_beta    = (const float*)d_in[11];  // (1024,)
  float* out = (float*)d_out;                        // (4,2048,1024) f32 OUTPUT

  // workspace layout (MiB offsets) — total 164 MiB (R4 proved writes < 192 MiB
  // safe; R1/R3 faulted at 260/272 MiB → ws_size ≈ 256 MiB, stay well under).
  //   @0    xi_raw  f32 64 MiB   -> reused as ybuf after conv
  //   @64M  xi_post f32 64 MiB
  //   @128M zbuf    bf16 32 MiB  -> reused as preln f32 32 MiB after scan
  //   @160M dbc     f32  4 MiB
  char* ws = (char*)d_ws;
  float* xi_raw  = (float*)(ws + 0);
  float* xi_post = (float*)(ws + (size_t) 67108864);
  u16*   zbuf    = (u16*)  (ws + (size_t)134217728);
  float* dbc     = (float*)(ws + (size_t)167772160);
  float* ybuf    = xi_raw;              // xi_raw dead after conv
  float* preln   = (float*)(ws + (size_t)134217728);  // zbuf dead after scan

  // 1a) xi_raw = x @ in_proj_w[:, :2048]     M=8192 N=2048 K=1024 (f32 out)
  {
    dim3 grid(D_INNER/128, NTOK/128);
    sgemm<128,128,8,8,8,false><<<grid,256,0,stream>>>(D_MODEL,
        x,D_MODEL, in_proj_w,2*D_INNER, xi_raw,D_INNER);
  }
  // 1b) z = x @ in_proj_w[:, 2048:]          M=8192 N=2048 K=1024 (bf16 out)
  {
    dim3 grid(D_INNER/128, NTOK/128);
    sgemm<128,128,8,8,8,true><<<grid,256,0,stream>>>(D_MODEL,
        x,D_MODEL, in_proj_w + D_INNER,2*D_INNER, zbuf,D_INNER);
  }
  // 2) xi_post = silu(conv(xi_raw) + conv_b)
  conv_silu_kernel<<<(NTOK*(size_t)D_INNER)/256,256,0,stream>>>(xi_raw, conv_w, conv_b, xi_post);

  // 3) dbc = xi_post @ x_proj_w              M=8192 N=128 K=2048 (f32 out)
  {
    dim3 grid(DBC_N/64, NTOK/64);
    sgemm<64,64,16,4,4,false><<<grid,256,0,stream>>>(D_INNER,
        xi_post,D_INNER, x_proj_w,DBC_N, dbc,DBC_N);
  }
  // 4) fused dt_proj + softplus + selective scan + D-skip + z-gate -> y (f32)
  scan_kernel<<<BATCH*256,256,0,stream>>>(dbc, xi_post, zbuf, ybuf,
                                          dt_proj_w, dt_proj_b, A_log, Dp);

  // 5) preln = y @ out_proj_w                M=8192 N=1024 K=2048 (f32 out)
  {
    dim3 grid(D_MODEL/128, NTOK/128);
    sgemm<128,128,8,8,8,false><<<grid,256,0,stream>>>(D_INNER,
        ybuf,D_INNER, out_proj_w,D_MODEL, preln,D_MODEL);
  }
  // 6) LayerNorm: preln f32 -> out f32
  ln_kernel<<<NTOK,256,0,stream>>>(preln, out, ln_gamma, ln_beta);
}

// Round 7
// 1873.814 us; speedup vs baseline: 2.3089x; 2.3089x over previous
//
#include <hip/hip_runtime.h>
#include <math.h>

#define D_MODEL 1024
#define D_STATE 32
#define D_CONV  4
#define D_INNER 2048
#define DT_RANK 64
#define BATCH   4
#define SEQ     2048
#define NTOK    (BATCH*SEQ)            // 8192 rows
#define DBC_N   (DT_RANK + 2*D_STATE)  // 128
#define NC      16                     // scan chunks
#define CL      (SEQ/NC)               // 128 steps per chunk

typedef unsigned short u16;

__device__ __forceinline__ float bf2f(u16 u){
  return __uint_as_float(((unsigned)u) << 16);
}
__device__ __forceinline__ u16 f2bf(float f){   // round-to-nearest-even
  unsigned u = __float_as_uint(f);
  return (u16)((u + 0x7fffu + ((u >> 16) & 1u)) >> 16);
}
__device__ __forceinline__ float sigmoidf_(float x){ return 1.f/(1.f+__expf(-x)); }

// ---------------------------------------------------------------------------
// f32 tiled GEMM: C[M,N] = A[M,K] @ B[K,N]  (row-major, runtime ld)
// EPI: 0 plain, 1 softplus(acc + bias[col]).  CBF: store bf16 vs f32.
// Requires: BM*BK == BN*BK == 1024 == 4 * blockDim (256 thr * float4)
// ---------------------------------------------------------------------------
template<int BM,int BN,int BK,int TM,int TN,int EPI,bool CBF>
__global__ __launch_bounds__((BM/TM)*(BN/TN))
void sgemm(int K,
           const float* __restrict__ A,int lda,
           const float* __restrict__ B,int ldb,
           void* __restrict__ Cv,int ldc,
           const float* __restrict__ bias)
{
  __shared__ float As[BK][BM];
  __shared__ float Bs[BK][BN];
  const int tid  = threadIdx.x;
  const int brow = blockIdx.y, bcol = blockIdx.x;
  const int tcol = tid % (BN/TN);
  const int trow = tid / (BN/TN);

  const float* Ag = A + (size_t)brow*BM*lda;
  const float* Bg = B + (size_t)bcol*BN;

  const int arow = tid / (BK/4);
  const int acol = (tid % (BK/4))*4;
  const int brw  = tid / (BN/4);
  const int bcv  = (tid % (BN/4))*4;

  float acc[TM][TN] = {};

  for (int k0=0; k0<K; k0+=BK){
    float4 av = *(const float4*)(Ag + (size_t)arow*lda + k0 + acol);
    float4 bv = *(const float4*)(Bg + (size_t)(k0+brw)*ldb + bcv);
    __syncthreads();
    As[acol+0][arow]=av.x; As[acol+1][arow]=av.y;
    As[acol+2][arow]=av.z; As[acol+3][arow]=av.w;
    *(float4*)&Bs[brw][bcv] = bv;
    __syncthreads();
    #pragma unroll
    for (int kk=0;kk<BK;kk++){
      float ra[TM], rb[TN];
      #pragma unroll
      for (int m=0;m<TM;m++) ra[m]=As[kk][trow*TM+m];
      #pragma unroll
      for (int n=0;n<TN;n++) rb[n]=Bs[kk][tcol*TN+n];
      #pragma unroll
      for (int m=0;m<TM;m++)
        #pragma unroll
        for (int n=0;n<TN;n++)
          acc[m][n] += ra[m]*rb[n];
    }
  }

  #pragma unroll
  for (int m=0;m<TM;m++){
    int row = brow*BM + trow*TM + m;
    #pragma unroll
    for (int n=0;n<TN;n++){
      int col = bcol*BN + tcol*TN + n;
      float v = acc[m][n];
      if (EPI==1){
        v += bias[col];
        v = (v > 20.f) ? v : log1pf(__expf(v));
      }
      if (CBF) ((u16*) Cv)[(size_t)row*ldc + col] = f2bf(v);
      else     ((float*)Cv)[(size_t)row*ldc + col] = v;
    }
  }
}

// ---------------------------------------------------------------------------
// Depthwise causal conv (K=4) + bias + SiLU. xi_raw (f32, ld 2048) -> xi_post.
// ---------------------------------------------------------------------------
__global__ __launch_bounds__(256)
void conv_silu_kernel(const float* __restrict__ xi_raw,
                      const float* __restrict__ conv_w,
                      const float* __restrict__ conv_b,
                      float* __restrict__ xi_post)
{
  size_t idx = (size_t)blockIdx.x*256 + threadIdx.x;   // over NTOK*D_INNER
  int d = (int)(idx % D_INNER);
  size_t bt = idx / D_INNER;
  int t = (int)(bt % SEQ);
  size_t b = bt / SEQ;
  const float* xi = xi_raw + b*(size_t)SEQ*D_INNER;
  float accv = conv_b[d];
  #pragma unroll
  for (int k=0;k<D_CONV;k++){
    int tt = t + k - (D_CONV-1);
    if (tt >= 0) accv += xi[(size_t)tt*D_INNER + d] * conv_w[d*D_CONV + k];
  }
  xi_post[idx] = accv * sigmoidf_(accv);
}

// ---------------------------------------------------------------------------
// Chunked selective scan, pass 1: lane = channel, h[32] in registers.
// Per (b, chunk, d): run recurrence from h=0 over CL steps; emit end-state
// q[32] and sumdl. No cross-lane ops at all.
// ---------------------------------------------------------------------------
__global__ __launch_bounds__(256)
void scan_part1(const float* __restrict__ dbc,     // (NTOK,128)
                const float* __restrict__ delta,   // (NTOK,D_INNER)
                const float* __restrict__ u,       // (NTOK,D_INNER)
                const float* __restrict__ A_log,   // (D_INNER,32)
                float* __restrict__ q,             // (B,NC,D_INNER,32)
                float* __restrict__ sumdl_buf)     // (B,NC,D_INNER)
{
  const int ndg  = D_INNER/256;                 // 8
  const int dgrp = blockIdx.x % ndg;
  const int c    = (blockIdx.x / ndg) % NC;
  const int b    =  blockIdx.x / (ndg*NC);
  const int d    = dgrp*256 + threadIdx.x;

  float A[D_STATE];
  #pragma unroll
  for (int g=0; g<8; ++g){
    float4 al = *(const float4*)(A_log + (size_t)d*D_STATE + 4*g);
    A[4*g+0] = -__expf(al.x); A[4*g+1] = -__expf(al.y);
    A[4*g+2] = -__expf(al.z); A[4*g+3] = -__expf(al.w);
  }

  const size_t tok0 = (size_t)b*SEQ + (size_t)c*CL;
  const float* dptr = delta + tok0*D_INNER + d;
  const float* uptr = u     + tok0*D_INNER + d;
  const float* dbcp = dbc   + tok0*DBC_N;

  float h[D_STATE] = {};
  float sumdl = 0.f;

  for (int t=0; t<CL; ++t){
    float dl = dptr[(size_t)t*D_INNER];
    float uu = uptr[(size_t)t*D_INNER];
    sumdl += dl;
    float w = dl*uu;
    const float4* B4 = (const float4*)(dbcp + (size_t)t*DBC_N + DT_RANK); // wave-uniform
    #pragma unroll
    for (int g=0; g<8; ++g){
      float4 Bv = B4[g];
      h[4*g+0] = __expf(dl*A[4*g+0])*h[4*g+0] + w*Bv.x;
      h[4*g+1] = __expf(dl*A[4*g+1])*h[4*g+1] + w*Bv.y;
      h[4*g+2] = __expf(dl*A[4*g+2])*h[4*g+2] + w*Bv.z;
      h[4*g+3] = __expf(dl*A[4*g+3])*h[4*g+3] + w*Bv.w;
    }
  }

  float* qp = q + (((size_t)b*NC + c)*D_INNER + d)*D_STATE;
  #pragma unroll
  for (int g=0; g<8; ++g)
    ((float4*)qp)[g] = make_float4(h[4*g+0],h[4*g+1],h[4*g+2],h[4*g+3]);
  sumdl_buf[((size_t)b*NC + c)*D_INNER + d] = sumdl;
}

// ---------------------------------------------------------------------------
// Pass 2: sequential combine across chunks, in-place on q.
// Thread = (b,d,s). After this, q[b][c][d][s] = h_in for chunk c.
// ---------------------------------------------------------------------------
__global__ __launch_bounds__(256)
void scan_combine(float* __restrict__ q,
                  const float* __restrict__ sumdl_buf,
                  const float* __restrict__ A_log)
{
  size_t idx = (size_t)blockIdx.x*256 + threadIdx.x;   // over B*D_INNER*32
  int s = (int)(idx % D_STATE);
  size_t dd = idx / D_STATE;
  int d = (int)(dd % D_INNER);
  int b = (int)(dd / D_INNER);

  const float As = -__expf(A_log[(size_t)d*D_STATE + s]);
  float H = 0.f;
  for (int c=0; c<NC; ++c){
    size_t off = (((size_t)b*NC + c)*D_INNER + d)*D_STATE + s;
    float tmp = q[off];          // chunk-local end state (zero init)
    q[off] = H;                  // h_in for chunk c
    H = __expf(As * sumdl_buf[((size_t)b*NC + c)*D_INNER + d]) * H + tmp;
  }
}

// ---------------------------------------------------------------------------
// Pass 3: re-run recurrence per chunk from h_in; y = sum_s h*C (in-register),
// fused D-skip + z-gate; y written IN-PLACE over delta (same (b,t,d) slot).
// ---------------------------------------------------------------------------
__global__ __launch_bounds__(256)
void scan_part2(const float* __restrict__ dbc,     // (NTOK,128)
                float* __restrict__ delta_y,       // in: delta, out: y
                const float* __restrict__ u,
                const u16*   __restrict__ z,       // bf16
                const float* __restrict__ q,       // h_in per chunk
                const float* __restrict__ A_log,
                const float* __restrict__ Dp)
{
  const int ndg  = D_INNER/256;
  const int dgrp = blockIdx.x % ndg;
  const int c    = (blockIdx.x / ndg) % NC;
  const int b    =  blockIdx.x / (ndg*NC);
  const int d    = dgrp*256 + threadIdx.x;

  float A[D_STATE];
  #pragma unroll
  for (int g=0; g<8; ++g){
    float4 al = *(const float4*)(A_log + (size_t)d*D_STATE + 4*g);
    A[4*g+0] = -__expf(al.x); A[4*g+1] = -__expf(al.y);
    A[4*g+2] = -__expf(al.z); A[4*g+3] = -__expf(al.w);
  }
  float h[D_STATE];
  const float* qp = q + (((size_t)b*NC + c)*D_INNER + d)*D_STATE;
  #pragma unroll
  for (int g=0; g<8; ++g){
    float4 hv = ((const float4*)qp)[g];
    h[4*g+0]=hv.x; h[4*g+1]=hv.y; h[4*g+2]=hv.z; h[4*g+3]=hv.w;
  }
  const float Dd = Dp[d];

  const size_t tok0 = (size_t)b*SEQ + (size_t)c*CL;
  float*       dyp  = delta_y + tok0*D_INNER + d;
  const float* uptr = u       + tok0*D_INNER + d;
  const u16*   zptr = z       + tok0*D_INNER + d;
  const float* dbcp = dbc     + tok0*DBC_N;

  for (int t=0; t<CL; ++t){
    float dl = dyp[(size_t)t*D_INNER];
    float uu = uptr[(size_t)t*D_INNER];
    float zz = bf2f(zptr[(size_t)t*D_INNER]);
    float w  = dl*uu;
    const float4* B4 = (const float4*)(dbcp + (size_t)t*DBC_N + DT_RANK);
    const float4* C4 = B4 + 8;   // C at offset 96 floats
    float y = 0.f;
    #pragma unroll
    for (int g=0; g<8; ++g){
      float4 Bv = B4[g];
      float4 Cv = C4[g];
      h[4*g+0] = __expf(dl*A[4*g+0])*h[4*g+0] + w*Bv.x;  y += h[4*g+0]*Cv.x;
      h[4*g+1] = __expf(dl*A[4*g+1])*h[4*g+1] + w*Bv.y;  y += h[4*g+1]*Cv.y;
      h[4*g+2] = __expf(dl*A[4*g+2])*h[4*g+2] + w*Bv.z;  y += h[4*g+2]*Cv.z;
      h[4*g+3] = __expf(dl*A[4*g+3])*h[4*g+3] + w*Bv.w;  y += h[4*g+3]*Cv.w;
    }
    dyp[(size_t)t*D_INNER] = (y + uu*Dd) * (zz * sigmoidf_(zz));
  }
}

// ---------------------------------------------------------------------------
// LayerNorm over last dim (1024): read f32 pre-LN, write f32 output.
// ---------------------------------------------------------------------------
__global__ __launch_bounds__(256)
void ln_kernel(const float* __restrict__ in,
               float* __restrict__ out,
               const float* __restrict__ gamma,
               const float* __restrict__ beta)
{
  const int row = blockIdx.x;
  const float* p = in + (size_t)row*D_MODEL;
  float* q = out + (size_t)row*D_MODEL;
  float v[4]; float s=0.f, ss=0.f;
  #pragma unroll
  for (int i=0;i<4;i++){
    float x = p[i*256 + threadIdx.x];
    v[i]=x; s+=x; ss+=x*x;
  }
  #pragma unroll
  for (int off=32; off; off>>=1){
    s  += __shfl_xor(s,  off, 64);
    ss += __shfl_xor(ss, off, 64);
  }
  __shared__ float sw[4], ssw[4];
  const int wid = threadIdx.x >> 6;
  if ((threadIdx.x & 63) == 0){ sw[wid]=s; ssw[wid]=ss; }
  __syncthreads();
  s  = sw[0]+sw[1]+sw[2]+sw[3];
  ss = ssw[0]+ssw[1]+ssw[2]+ssw[3];
  const float mu  = s * (1.f/D_MODEL);
  const float var = ss * (1.f/D_MODEL) - mu*mu;
  const float inv = rsqrtf(var + 1e-5f);
  #pragma unroll
  for (int i=0;i<4;i++){
    int col = i*256 + threadIdx.x;
    q[col] = (v[i]-mu)*inv*gamma[col] + beta[col];
  }
}

// ---------------------------------------------------------------------------
extern "C" void kernel_launch(void* const* d_in, const int* in_sizes, int n_in,
                              void* d_out, int out_size, void* d_ws, size_t ws_size,
                              hipStream_t stream)
{
  const float* x          = (const float*)d_in[0];   // (4,2048,1024) f32
  const float* in_proj_w  = (const float*)d_in[1];   // (1024,4096)
  const float* conv_w     = (const float*)d_in[2];   // (2048,4)
  const float* conv_b     = (const float*)d_in[3];   // (2048,)
  const float* x_proj_w   = (const float*)d_in[4];   // (2048,128)
  const float* dt_proj_w  = (const float*)d_in[5];   // (64,2048)
  const float* dt_proj_b  = (const float*)d_in[6];   // (2048,)
  const float* A_log      = (const float*)d_in[7];   // (2048,32)
  const float* Dp         = (const float*)d_in[8];   // (2048,)
  const float* out_proj_w = (const float*)d_in[9];   // (2048,1024)
  const float* ln_gamma   = (const float*)d_in[10];  // (1024,)
  const float* ln_beta    = (const float*)d_in[11];  // (1024,)
  float* out = (float*)d_out;                        // (4,2048,1024) f32 OUTPUT

  // workspace layout — peak 180.5 MiB, inside the R4-proven <192 MiB zone.
  //   @0    xi_raw f32 64 MiB -> (dead after conv) delta f32 -> (in-place) y f32
  //   @64M  xi_post f32 64 MiB
  //   @128M zbuf bf16 32 MiB  -> (dead after S3) preln f32 32 MiB
  //   @160M dbc f32 4 MiB
  //   @164M q f32 16 MiB (B,NC,D_INNER,32)
  //   @180M sumdl f32 0.5 MiB
  char* ws = (char*)d_ws;
  float* xi_raw  = (float*)(ws + 0);
  float* xi_post = (float*)(ws + (size_t) 67108864);
  u16*   zbuf    = (u16*)  (ws + (size_t)134217728);
  float* dbc     = (float*)(ws + (size_t)167772160);
  float* qbuf    = (float*)(ws + (size_t)171966464);
  float* sumdl   = (float*)(ws + (size_t)188743680);
  float* deltab  = xi_raw;                            // over dead xi_raw
  float* ybuf    = xi_raw;                            // in-place over delta (S3)
  float* preln   = (float*)(ws + (size_t)134217728);  // over dead zbuf

  // 1a) xi_raw = x @ in_proj_w[:, :2048]     M=8192 N=2048 K=1024 (f32 out)
  {
    dim3 grid(D_INNER/128, NTOK/128);
    sgemm<128,128,8,8,8,0,false><<<grid,256,0,stream>>>(D_MODEL,
        x,D_MODEL, in_proj_w,2*D_INNER, xi_raw,D_INNER, nullptr);
  }
  // 1b) z = x @ in_proj_w[:, 2048:]          M=8192 N=2048 K=1024 (bf16 out)
  {
    dim3 grid(D_INNER/128, NTOK/128);
    sgemm<128,128,8,8,8,0,true><<<grid,256,0,stream>>>(D_MODEL,
        x,D_MODEL, in_proj_w + D_INNER,2*D_INNER, zbuf,D_INNER, nullptr);
  }
  // 2) xi_post = silu(conv(xi_raw) + conv_b)  (xi_raw dead after this)
  conv_silu_kernel<<<(NTOK*(size_t)D_INNER)/256,256,0,stream>>>(xi_raw, conv_w, conv_b, xi_post);

  // 3) dbc = xi_post @ x_proj_w              M=8192 N=128 K=2048 (f32 out)
  {
    dim3 grid(DBC_N/64, NTOK/64);
    sgemm<64,64,16,4,4,0,false><<<grid,256,0,stream>>>(D_INNER,
        xi_post,D_INNER, x_proj_w,DBC_N, dbc,DBC_N, nullptr);
  }
  // 4) delta = softplus(dbc[:, :64] @ dt_proj_w + b)  M=8192 N=2048 K=64 -> @0
  {
    dim3 grid(D_INNER/64, NTOK/64);
    sgemm<64,64,16,4,4,1,false><<<grid,256,0,stream>>>(DT_RANK,
        dbc,DBC_N, dt_proj_w,D_INNER, deltab,D_INNER, dt_proj_b);
  }
  // 5) chunked scan: S1 (local scans) -> S2 (combine) -> S3 (emit y, fused gate)
  {
    dim3 grid1((D_INNER/256)*NC*BATCH);           // 512 blocks
    scan_part1<<<grid1,256,0,stream>>>(dbc, deltab, xi_post, A_log, qbuf, sumdl);
    scan_combine<<<(BATCH*(size_t)D_INNER*D_STATE)/256,256,0,stream>>>(qbuf, sumdl, A_log);
    scan_part2<<<grid1,256,0,stream>>>(dbc, deltab, xi_post, zbuf, qbuf, A_log, Dp);
  }
  // 6) preln = y @ out_proj_w                M=8192 N=1024 K=2048 (f32 out)
  {
    dim3 grid(D_MODEL/128, NTOK/128);
    sgemm<128,128,8,8,8,0,false><<<grid,256,0,stream>>>(D_INNER,
        ybuf,D_INNER, out_proj_w,D_MODEL, preln,D_MODEL, nullptr);
  }
  // 7) LayerNorm: preln f32 -> out f32
  ln_kernel<<<NTOK,256,0,stream>>>(preln, out, ln_gamma, ln_beta);
}

// Round 8
// 858.630 us; speedup vs baseline: 5.0387x; 2.1823x over previous
//
#include <hip/hip_runtime.h>
#include <math.h>

#define D_MODEL 1024
#define D_STATE 32
#define D_CONV  4
#define D_INNER 2048
#define DT_RANK 64
#define BATCH   4
#define SEQ     2048
#define NTOK    (BATCH*SEQ)            // 8192 rows
#define DBC_N   (DT_RANK + 2*D_STATE)  // 128
#define NC      16                     // scan chunks
#define CL      (SEQ/NC)               // 128 steps per chunk
#define LDK     40                     // padded LDS row (elems) for MFMA tiles

typedef unsigned short u16;
typedef short bf16x8 __attribute__((ext_vector_type(8)));
typedef float f32x4  __attribute__((ext_vector_type(4)));
typedef u16   u16x8  __attribute__((ext_vector_type(8)));

__device__ __forceinline__ float bf2f(u16 u){
  return __uint_as_float(((unsigned)u) << 16);
}
__device__ __forceinline__ u16 f2bf(float f){   // round-to-nearest-even
  unsigned u = __float_as_uint(f);
  return (u16)((u + 0x7fffu + ((u >> 16) & 1u)) >> 16);
}
__device__ __forceinline__ float sigmoidf_(float x){ return 1.f/(1.f+__expf(-x)); }

// ---------------------------------------------------------------------------
// bf16 MFMA GEMM: C[M,N] = A[M,K] @ W[K,N], where A is bf16 row-major [M][K]
// and B is the WEIGHT PRE-TRANSPOSED bf16 [N][K]. 128x128 tile, BK=32,
// 4 waves of 64x64 (4x4 MFMA 16x16x32). CBF: store bf16 else f32.
// ---------------------------------------------------------------------------
template<bool CBF>
__global__ __launch_bounds__(256)
void mfma_gemm(int K,
               const u16* __restrict__ A, int lda,
               const u16* __restrict__ B, int ldb,   // [N][K]
               void* __restrict__ Cv, int ldc)
{
  __shared__ u16 As[128*LDK];
  __shared__ u16 Bs[128*LDK];
  const int tid  = threadIdx.x;
  const int lane = tid & 63;
  const int wave = tid >> 6;
  const int wm = (wave>>1)*64, wn = (wave&1)*64;
  const int m0 = blockIdx.y*128, n0 = blockIdx.x*128;

  // staging map: 256 thr × 2 chunks of 16B each for A and B tiles (128x32 bf16)
  const int sr = tid >> 2;          // 0..63
  const int sc = (tid & 3) * 8;     // elem offset within 32-wide K slice

  const u16* Ag = A + (size_t)m0*lda;
  const u16* Bg = B + (size_t)n0*ldb;

  const int fr = lane & 15;         // fragment row within 16
  const int fq = lane >> 4;         // quad: k-chunk of 8
  f32x4 acc[4][4] = {};

  for (int k0=0; k0<K; k0+=32){
    u16x8 a0 = *(const u16x8*)(Ag + (size_t) sr    *lda + k0 + sc);
    u16x8 a1 = *(const u16x8*)(Ag + (size_t)(sr+64)*lda + k0 + sc);
    u16x8 b0 = *(const u16x8*)(Bg + (size_t) sr    *ldb + k0 + sc);
    u16x8 b1 = *(const u16x8*)(Bg + (size_t)(sr+64)*ldb + k0 + sc);
    __syncthreads();
    *(u16x8*)&As[ sr    *LDK + sc] = a0;
    *(u16x8*)&As[(sr+64)*LDK + sc] = a1;
    *(u16x8*)&Bs[ sr    *LDK + sc] = b0;
    *(u16x8*)&Bs[(sr+64)*LDK + sc] = b1;
    __syncthreads();

    bf16x8 af[4], bfr[4];
    #pragma unroll
    for (int i=0;i<4;i++){
      af[i]  = *(const bf16x8*)&As[(wm + i*16 + fr)*LDK + fq*8];
      bfr[i] = *(const bf16x8*)&Bs[(wn + i*16 + fr)*LDK + fq*8];
    }
    #pragma unroll
    for (int mi=0;mi<4;mi++)
      #pragma unroll
      for (int ni=0;ni<4;ni++)
        acc[mi][ni] = __builtin_amdgcn_mfma_f32_16x16x32_bf16(
            af[mi], bfr[ni], acc[mi][ni], 0, 0, 0);
  }

  // C/D layout: row = fq*4 + r, col = fr  (m89-verified)
  #pragma unroll
  for (int mi=0;mi<4;mi++){
    #pragma unroll
    for (int ni=0;ni<4;ni++){
      int col = n0 + wn + ni*16 + fr;
      #pragma unroll
      for (int r=0;r<4;r++){
        int row = m0 + wm + mi*16 + fq*4 + r;
        if (CBF) ((u16*) Cv)[(size_t)row*ldc + col] = f2bf(acc[mi][ni][r]);
        else     ((float*)Cv)[(size_t)row*ldc + col] = acc[mi][ni][r];
      }
    }
  }
}

// ---------------------------------------------------------------------------
// f32 -> bf16 elementwise (n multiple of 1024)
// ---------------------------------------------------------------------------
__global__ __launch_bounds__(256)
void cvt_f32_bf16(const float* __restrict__ in, u16* __restrict__ out)
{
  size_t i = (size_t)blockIdx.x*256 + threadIdx.x;
  float4 v = ((const float4*)in)[i];
  ushort4 o;
  o.x=f2bf(v.x); o.y=f2bf(v.y); o.z=f2bf(v.z); o.w=f2bf(v.w);
  ((ushort4*)out)[i] = o;
}

// ---------------------------------------------------------------------------
// f32 [R][C] -> bf16 [C][R] transpose+convert, 64x64 tiles, 256 threads.
// ---------------------------------------------------------------------------
__global__ __launch_bounds__(256)
void transpose_cvt(const float* __restrict__ in, u16* __restrict__ out,
                   int R, int C)
{
  __shared__ float tile[64][65];
  const int bc = blockIdx.x*64, br = blockIdx.y*64;
  const int tx = threadIdx.x & 63, ty = threadIdx.x >> 6;
  #pragma unroll
  for (int i=0;i<16;i++){
    int r = ty + i*4;
    tile[r][tx] = in[(size_t)(br+r)*C + bc+tx];
  }
  __syncthreads();
  #pragma unroll
  for (int i=0;i<16;i++){
    int r = ty + i*4;
    out[(size_t)(bc+r)*R + br+tx] = f2bf(tile[tx][r]);
  }
}

// ---------------------------------------------------------------------------
// f32 tiled GEMM (small shapes): C[M,N] = A[M,K] @ B[K,N]
// EPI: 0 plain, 1 softplus(acc + bias[col]).
// ---------------------------------------------------------------------------
template<int BM,int BN,int BK,int TM,int TN,int EPI>
__global__ __launch_bounds__((BM/TM)*(BN/TN))
void sgemm(int K,
           const float* __restrict__ A,int lda,
           const float* __restrict__ B,int ldb,
           float* __restrict__ C,int ldc,
           const float* __restrict__ bias)
{
  __shared__ float As[BK][BM];
  __shared__ float Bs[BK][BN];
  const int tid  = threadIdx.x;
  const int brow = blockIdx.y, bcol = blockIdx.x;
  const int tcol = tid % (BN/TN);
  const int trow = tid / (BN/TN);

  const float* Ag = A + (size_t)brow*BM*lda;
  const float* Bg = B + (size_t)bcol*BN;

  const int arow = tid / (BK/4);
  const int acol = (tid % (BK/4))*4;
  const int brw  = tid / (BN/4);
  const int bcv  = (tid % (BN/4))*4;

  float acc[TM][TN] = {};

  for (int k0=0; k0<K; k0+=BK){
    float4 av = *(const float4*)(Ag + (size_t)arow*lda + k0 + acol);
    float4 bv = *(const float4*)(Bg + (size_t)(k0+brw)*ldb + bcv);
    __syncthreads();
    As[acol+0][arow]=av.x; As[acol+1][arow]=av.y;
    As[acol+2][arow]=av.z; As[acol+3][arow]=av.w;
    *(float4*)&Bs[brw][bcv] = bv;
    __syncthreads();
    #pragma unroll
    for (int kk=0;kk<BK;kk++){
      float ra[TM], rb[TN];
      #pragma unroll
      for (int m=0;m<TM;m++) ra[m]=As[kk][trow*TM+m];
      #pragma unroll
      for (int n=0;n<TN;n++) rb[n]=Bs[kk][tcol*TN+n];
      #pragma unroll
      for (int m=0;m<TM;m++)
        #pragma unroll
        for (int n=0;n<TN;n++)
          acc[m][n] += ra[m]*rb[n];
    }
  }

  #pragma unroll
  for (int m=0;m<TM;m++){
    int row = brow*BM + trow*TM + m;
    #pragma unroll
    for (int n=0;n<TN;n++){
      int col = bcol*BN + tcol*TN + n;
      float v = acc[m][n];
      if (EPI==1){
        v += bias[col];
        v = (v > 20.f) ? v : log1pf(__expf(v));
      }
      C[(size_t)row*ldc + col] = v;
    }
  }
}

// ---------------------------------------------------------------------------
// Depthwise causal conv (K=4) + bias + SiLU. xi_raw (f32, ld 2048) -> xi_post.
// ---------------------------------------------------------------------------
__global__ __launch_bounds__(256)
void conv_silu_kernel(const float* __restrict__ xi_raw,
                      const float* __restrict__ conv_w,
                      const float* __restrict__ conv_b,
                      float* __restrict__ xi_post)
{
  size_t idx = (size_t)blockIdx.x*256 + threadIdx.x;   // over NTOK*D_INNER
  int d = (int)(idx % D_INNER);
  size_t bt = idx / D_INNER;
  int t = (int)(bt % SEQ);
  size_t b = bt / SEQ;
  const float* xi = xi_raw + b*(size_t)SEQ*D_INNER;
  float accv = conv_b[d];
  #pragma unroll
  for (int k=0;k<D_CONV;k++){
    int tt = t + k - (D_CONV-1);
    if (tt >= 0) accv += xi[(size_t)tt*D_INNER + d] * conv_w[d*D_CONV + k];
  }
  xi_post[idx] = accv * sigmoidf_(accv);
}

// ---------------------------------------------------------------------------
// Chunked selective scan, pass 1: lane = channel, h[32] in registers.
// ---------------------------------------------------------------------------
__global__ __launch_bounds__(256)
void scan_part1(const float* __restrict__ dbc,     // (NTOK,128)
                const float* __restrict__ delta,   // (NTOK,D_INNER)
                const float* __restrict__ u,       // (NTOK,D_INNER)
                const float* __restrict__ A_log,   // (D_INNER,32)
                float* __restrict__ q,             // (B,NC,D_INNER,32)
                float* __restrict__ sumdl_buf)     // (B,NC,D_INNER)
{
  const int ndg  = D_INNER/256;                 // 8
  const int dgrp = blockIdx.x % ndg;
  const int c    = (blockIdx.x / ndg) % NC;
  const int b    =  blockIdx.x / (ndg*NC);
  const int d    = dgrp*256 + threadIdx.x;

  float A[D_STATE];
  #pragma unroll
  for (int g=0; g<8; ++g){
    float4 al = *(const float4*)(A_log + (size_t)d*D_STATE + 4*g);
    A[4*g+0] = -__expf(al.x); A[4*g+1] = -__expf(al.y);
    A[4*g+2] = -__expf(al.z); A[4*g+3] = -__expf(al.w);
  }

  const size_t tok0 = (size_t)b*SEQ + (size_t)c*CL;
  const float* dptr = delta + tok0*D_INNER + d;
  const float* uptr = u     + tok0*D_INNER + d;
  const float* dbcp = dbc   + tok0*DBC_N;

  float h[D_STATE] = {};
  float sumdl = 0.f;

  for (int t=0; t<CL; ++t){
    float dl = dptr[(size_t)t*D_INNER];
    float uu = uptr[(size_t)t*D_INNER];
    sumdl += dl;
    float w = dl*uu;
    const float4* B4 = (const float4*)(dbcp + (size_t)t*DBC_N + DT_RANK);
    #pragma unroll
    for (int g=0; g<8; ++g){
      float4 Bv = B4[g];
      h[4*g+0] = __expf(dl*A[4*g+0])*h[4*g+0] + w*Bv.x;
      h[4*g+1] = __expf(dl*A[4*g+1])*h[4*g+1] + w*Bv.y;
      h[4*g+2] = __expf(dl*A[4*g+2])*h[4*g+2] + w*Bv.z;
      h[4*g+3] = __expf(dl*A[4*g+3])*h[4*g+3] + w*Bv.w;
    }
  }

  float* qp = q + (((size_t)b*NC + c)*D_INNER + d)*D_STATE;
  #pragma unroll
  for (int g=0; g<8; ++g)
    ((float4*)qp)[g] = make_float4(h[4*g+0],h[4*g+1],h[4*g+2],h[4*g+3]);
  sumdl_buf[((size_t)b*NC + c)*D_INNER + d] = sumdl;
}

// ---------------------------------------------------------------------------
// Pass 2: sequential combine across chunks, in-place on q.
// ---------------------------------------------------------------------------
__global__ __launch_bounds__(256)
void scan_combine(float* __restrict__ q,
                  const float* __restrict__ sumdl_buf,
                  const float* __restrict__ A_log)
{
  size_t idx = (size_t)blockIdx.x*256 + threadIdx.x;   // over B*D_INNER*32
  int s = (int)(idx % D_STATE);
  size_t dd = idx / D_STATE;
  int d = (int)(dd % D_INNER);
  int b = (int)(dd / D_INNER);

  const float As = -__expf(A_log[(size_t)d*D_STATE + s]);
  float H = 0.f;
  for (int c=0; c<NC; ++c){
    size_t off = (((size_t)b*NC + c)*D_INNER + d)*D_STATE + s;
    float tmp = q[off];          // chunk-local end state
    q[off] = H;                  // h_in for chunk c
    H = __expf(As * sumdl_buf[((size_t)b*NC + c)*D_INNER + d]) * H + tmp;
  }
}

// ---------------------------------------------------------------------------
// Pass 3: re-run recurrence from h_in; y = sum_s h*C, fused D-skip + z-gate.
// z is read bf16 and y (bf16) is written IN-PLACE over it (same slot, same
// thread -> race-free). y then feeds the out_proj MFMA directly.
// ---------------------------------------------------------------------------
__global__ __launch_bounds__(256)
void scan_part2(const float* __restrict__ dbc,     // (NTOK,128)
                const float* __restrict__ delta,   // (NTOK,D_INNER)
                const float* __restrict__ u,
                u16*         __restrict__ zy,      // in: z bf16, out: y bf16
                const float* __restrict__ q,       // h_in per chunk
                const float* __restrict__ A_log,
                const float* __restrict__ Dp)
{
  const int ndg  = D_INNER/256;
  const int dgrp = blockIdx.x % ndg;
  const int c    = (blockIdx.x / ndg) % NC;
  const int b    =  blockIdx.x / (ndg*NC);
  const int d    = dgrp*256 + threadIdx.x;

  float A[D_STATE];
  #pragma unroll
  for (int g=0; g<8; ++g){
    float4 al = *(const float4*)(A_log + (size_t)d*D_STATE + 4*g);
    A[4*g+0] = -__expf(al.x); A[4*g+1] = -__expf(al.y);
    A[4*g+2] = -__expf(al.z); A[4*g+3] = -__expf(al.w);
  }
  float h[D_STATE];
  const float* qp = q + (((size_t)b*NC + c)*D_INNER + d)*D_STATE;
  #pragma unroll
  for (int g=0; g<8; ++g){
    float4 hv = ((const float4*)qp)[g];
    h[4*g+0]=hv.x; h[4*g+1]=hv.y; h[4*g+2]=hv.z; h[4*g+3]=hv.w;
  }
  const float Dd = Dp[d];

  const size_t tok0 = (size_t)b*SEQ + (size_t)c*CL;
  const float* dptr = delta + tok0*D_INNER + d;
  const float* uptr = u     + tok0*D_INNER + d;
  u16*         zp   = zy    + tok0*D_INNER + d;
  const float* dbcp = dbc   + tok0*DBC_N;

  for (int t=0; t<CL; ++t){
    float dl = dptr[(size_t)t*D_INNER];
    float uu = uptr[(size_t)t*D_INNER];
    float zz = bf2f(zp[(size_t)t*D_INNER]);
    float w  = dl*uu;
    const float4* B4 = (const float4*)(dbcp + (size_t)t*DBC_N + DT_RANK);
    const float4* C4 = B4 + 8;
    float y = 0.f;
    #pragma unroll
    for (int g=0; g<8; ++g){
      float4 Bv = B4[g];
      float4 Cv = C4[g];
      h[4*g+0] = __expf(dl*A[4*g+0])*h[4*g+0] + w*Bv.x;  y += h[4*g+0]*Cv.x;
      h[4*g+1] = __expf(dl*A[4*g+1])*h[4*g+1] + w*Bv.y;  y += h[4*g+1]*Cv.y;
      h[4*g+2] = __expf(dl*A[4*g+2])*h[4*g+2] + w*Bv.z;  y += h[4*g+2]*Cv.z;
      h[4*g+3] = __expf(dl*A[4*g+3])*h[4*g+3] + w*Bv.w;  y += h[4*g+3]*Cv.w;
    }
    zp[(size_t)t*D_INNER] = f2bf((y + uu*Dd) * (zz * sigmoidf_(zz)));
  }
}

// ---------------------------------------------------------------------------
// LayerNorm over last dim (1024): read f32 pre-LN, write f32 output.
// ---------------------------------------------------------------------------
__global__ __launch_bounds__(256)
void ln_kernel(const float* __restrict__ in,
               float* __restrict__ out,
               const float* __restrict__ gamma,
               const float* __restrict__ beta)
{
  const int row = blockIdx.x;
  const float* p = in + (size_t)row*D_MODEL;
  float* q = out + (size_t)row*D_MODEL;
  float v[4]; float s=0.f, ss=0.f;
  #pragma unroll
  for (int i=0;i<4;i++){
    float x = p[i*256 + threadIdx.x];
    v[i]=x; s+=x; ss+=x*x;
  }
  #pragma unroll
  for (int off=32; off; off>>=1){
    s  += __shfl_xor(s,  off, 64);
    ss += __shfl_xor(ss, off, 64);
  }
  __shared__ float sw[4], ssw[4];
  const int wid = threadIdx.x >> 6;
  if ((threadIdx.x & 63) == 0){ sw[wid]=s; ssw[wid]=ss; }
  __syncthreads();
  s  = sw[0]+sw[1]+sw[2]+sw[3];
  ss = ssw[0]+ssw[1]+ssw[2]+ssw[3];
  const float mu  = s * (1.f/D_MODEL);
  const float var = ss * (1.f/D_MODEL) - mu*mu;
  const float inv = rsqrtf(var + 1e-5f);
  #pragma unroll
  for (int i=0;i<4;i++){
    int col = i*256 + threadIdx.x;
    q[col] = (v[i]-mu)*inv*gamma[col] + beta[col];
  }
}

// ---------------------------------------------------------------------------
extern "C" void kernel_launch(void* const* d_in, const int* in_sizes, int n_in,
                              void* d_out, int out_size, void* d_ws, size_t ws_size,
                              hipStream_t stream)
{
  const float* x          = (const float*)d_in[0];   // (4,2048,1024) f32
  const float* in_proj_w  = (const float*)d_in[1];   // (1024,4096)
  const float* conv_w     = (const float*)d_in[2];   // (2048,4)
  const float* conv_b     = (const float*)d_in[3];   // (2048,)
  const float* x_proj_w   = (const float*)d_in[4];   // (2048,128)
  const float* dt_proj_w  = (const float*)d_in[5];   // (64,2048)
  const float* dt_proj_b  = (const float*)d_in[6];   // (2048,)
  const float* A_log      = (const float*)d_in[7];   // (2048,32)
  const float* Dp         = (const float*)d_in[8];   // (2048,)
  const float* out_proj_w = (const float*)d_in[9];   // (2048,1024)
  const float* ln_gamma   = (const float*)d_in[10];  // (1024,)
  const float* ln_beta    = (const float*)d_in[11];  // (1024,)
  float* out = (float*)d_out;                        // (4,2048,1024) f32 OUTPUT

  // workspace (MiB offsets) — all writes within proven-safe [0, 192 MiB):
  //   @0    xi_raw f32 64M -> delta f32 -> (dead) -> preln f32 32M
  //   @64   xi_post f32 64M
  //   @128  z bf16 32M -> y bf16 (in-place, scan_part2)
  //   @160  x_bf 16M (G1 only) -> dbc f32 4M
  //   @164  qbuf f32 16M
  //   @180  w_inT bf16 8M (G1 only) -> sumdl f32 0.5M
  //   @188  w_outT bf16 4M
  char* ws = (char*)d_ws;
  float* xi_raw  = (float*)(ws + 0);
  float* deltab  = (float*)(ws + 0);
  float* preln   = (float*)(ws + 0);
  float* xi_post = (float*)(ws + (size_t) 67108864);
  u16*   zybuf   = (u16*)  (ws + (size_t)134217728);
  u16*   x_bf    = (u16*)  (ws + (size_t)167772160);
  float* dbc     = (float*)(ws + (size_t)167772160);
  float* qbuf    = (float*)(ws + (size_t)171966464);
  u16*   w_inT   = (u16*)  (ws + (size_t)188743680);
  float* sumdl   = (float*)(ws + (size_t)188743680);
  u16*   w_outT  = (u16*)  (ws + (size_t)197132288);

  // 0) dtype prep: x -> bf16; weights -> bf16 transposed [N][K]
  cvt_f32_bf16<<<(NTOK*(size_t)D_MODEL)/1024, 256, 0, stream>>>(x, x_bf);
  { dim3 g(4096/64, 1024/64); transpose_cvt<<<g,256,0,stream>>>(in_proj_w,  w_inT,  1024, 4096); }
  { dim3 g(1024/64, 2048/64); transpose_cvt<<<g,256,0,stream>>>(out_proj_w, w_outT, 2048, 1024); }

  // 1a) xi_raw = x @ in_proj_w[:, :2048]   (MFMA, f32 out)
  {
    dim3 grid(D_INNER/128, NTOK/128);
    mfma_gemm<false><<<grid,256,0,stream>>>(D_MODEL,
        x_bf, D_MODEL, w_inT, D_MODEL, xi_raw, D_INNER);
  }
  // 1b) z = x @ in_proj_w[:, 2048:]        (MFMA, bf16 out)
  {
    dim3 grid(D_INNER/128, NTOK/128);
    mfma_gemm<true><<<grid,256,0,stream>>>(D_MODEL,
        x_bf, D_MODEL, w_inT + (size_t)D_INNER*D_MODEL, D_MODEL, zybuf, D_INNER);
  }
  // 2) xi_post = silu(conv(xi_raw) + conv_b)
  conv_silu_kernel<<<(NTOK*(size_t)D_INNER)/256,256,0,stream>>>(xi_raw, conv_w, conv_b, xi_post);

  // 3) dbc = xi_post @ x_proj_w            M=8192 N=128 K=2048 (f32)
  {
    dim3 grid(DBC_N/64, NTOK/64);
    sgemm<64,64,16,4,4,0><<<grid,256,0,stream>>>(D_INNER,
        xi_post,D_INNER, x_proj_w,DBC_N, dbc,DBC_N, nullptr);
  }
  // 4) delta = softplus(dbc[:, :64] @ dt_proj_w + b)  M=8192 N=2048 K=64 -> @0
  {
    dim3 grid(D_INNER/64, NTOK/64);
    sgemm<64,64,16,4,4,1><<<grid,256,0,stream>>>(DT_RANK,
        dbc,DBC_N, dt_proj_w,D_INNER, deltab,D_INNER, dt_proj_b);
  }
  // 5) chunked scan; part2 writes y bf16 in-place over z
  {
    dim3 grid1((D_INNER/256)*NC*BATCH);           // 512 blocks
    scan_part1<<<grid1,256,0,stream>>>(dbc, deltab, xi_post, A_log, qbuf, sumdl);
    scan_combine<<<(BATCH*(size_t)D_INNER*D_STATE)/256,256,0,stream>>>(qbuf, sumdl, A_log);
    scan_part2<<<grid1,256,0,stream>>>(dbc, deltab, xi_post, zybuf, qbuf, A_log, Dp);
  }
  // 6) preln = y @ out_proj_w              (MFMA, f32 out) -> @0
  {
    dim3 grid(D_MODEL/128, NTOK/128);
    mfma_gemm<false><<<grid,256,0,stream>>>(D_INNER,
        zybuf, D_INNER, w_outT, D_INNER, preln, D_MODEL);
  }
  // 7) LayerNorm: preln f32 -> out f32
  ln_kernel<<<NTOK,256,0,stream>>>(preln, out, ln_gamma, ln_beta);
}

// Round 9
// 804.203 us; speedup vs baseline: 5.3797x; 1.0677x over previous
//
#include <hip/hip_runtime.h>
#include <math.h>

#define D_MODEL 1024
#define D_STATE 32
#define D_CONV  4
#define D_INNER 2048
#define DT_RANK 64
#define BATCH   4
#define SEQ     2048
#define NTOK    (BATCH*SEQ)            // 8192 rows
#define DBC_N   (DT_RANK + 2*D_STATE)  // 128
#define NC      64                     // scan chunks (R9: 16 -> 64 for occupancy)
#define CL      (SEQ/NC)               // 32 steps per chunk
#define LDK     40                     // padded LDS row (elems) for MFMA tiles

typedef unsigned short u16;
typedef short bf16x8 __attribute__((ext_vector_type(8)));
typedef float f32x4  __attribute__((ext_vector_type(4)));
typedef u16   u16x8  __attribute__((ext_vector_type(8)));

__device__ __forceinline__ float bf2f(u16 u){
  return __uint_as_float(((unsigned)u) << 16);
}
__device__ __forceinline__ u16 f2bf(float f){   // round-to-nearest-even
  unsigned u = __float_as_uint(f);
  return (u16)((u + 0x7fffu + ((u >> 16) & 1u)) >> 16);
}
__device__ __forceinline__ float sigmoidf_(float x){ return 1.f/(1.f+__expf(-x)); }

// ---------------------------------------------------------------------------
// bf16 MFMA GEMM: C = A[M,K] @ W[K,N], A bf16 row-major [M][K], B = weight
// PRE-TRANSPOSED bf16 [N][K]. 128x128 tile, BK=32, 4 waves of 64x64.
// MODE 0: f32 store to C1. MODE 1: bf16 store to C1.
// MODE 2 (split in_proj): col<D_INNER -> f32 C1; col>=D_INNER -> bf16 C2@col-2048.
// ---------------------------------------------------------------------------
template<int MODE>
__global__ __launch_bounds__(256)
void mfma_gemm(int K,
               const u16* __restrict__ A, int lda,
               const u16* __restrict__ B, int ldb,   // [N][K]
               void* __restrict__ C1, int ldc,
               u16*  __restrict__ C2)
{
  __shared__ u16 As[128*LDK];
  __shared__ u16 Bs[128*LDK];
  const int tid  = threadIdx.x;
  const int lane = tid & 63;
  const int wave = tid >> 6;
  const int wm = (wave>>1)*64, wn = (wave&1)*64;
  const int m0 = blockIdx.y*128, n0 = blockIdx.x*128;

  const int sr = tid >> 2;          // 0..63
  const int sc = (tid & 3) * 8;     // elem offset within 32-wide K slice

  const u16* Ag = A + (size_t)m0*lda;
  const u16* Bg = B + (size_t)n0*ldb;

  const int fr = lane & 15;         // fragment row within 16
  const int fq = lane >> 4;         // quad: k-chunk of 8
  f32x4 acc[4][4] = {};

  for (int k0=0; k0<K; k0+=32){
    u16x8 a0 = *(const u16x8*)(Ag + (size_t) sr    *lda + k0 + sc);
    u16x8 a1 = *(const u16x8*)(Ag + (size_t)(sr+64)*lda + k0 + sc);
    u16x8 b0 = *(const u16x8*)(Bg + (size_t) sr    *ldb + k0 + sc);
    u16x8 b1 = *(const u16x8*)(Bg + (size_t)(sr+64)*ldb + k0 + sc);
    __syncthreads();
    *(u16x8*)&As[ sr    *LDK + sc] = a0;
    *(u16x8*)&As[(sr+64)*LDK + sc] = a1;
    *(u16x8*)&Bs[ sr    *LDK + sc] = b0;
    *(u16x8*)&Bs[(sr+64)*LDK + sc] = b1;
    __syncthreads();

    bf16x8 af[4], bfr[4];
    #pragma unroll
    for (int i=0;i<4;i++){
      af[i]  = *(const bf16x8*)&As[(wm + i*16 + fr)*LDK + fq*8];
      bfr[i] = *(const bf16x8*)&Bs[(wn + i*16 + fr)*LDK + fq*8];
    }
    #pragma unroll
    for (int mi=0;mi<4;mi++)
      #pragma unroll
      for (int ni=0;ni<4;ni++)
        acc[mi][ni] = __builtin_amdgcn_mfma_f32_16x16x32_bf16(
            af[mi], bfr[ni], acc[mi][ni], 0, 0, 0);
  }

  // C/D layout: row = fq*4 + r, col = fr  (m89-verified)
  const bool second = (MODE==2) && (n0 >= D_INNER);   // block-uniform
  #pragma unroll
  for (int mi=0;mi<4;mi++){
    #pragma unroll
    for (int ni=0;ni<4;ni++){
      int col = n0 + wn + ni*16 + fr;
      #pragma unroll
      for (int r=0;r<4;r++){
        int row = m0 + wm + mi*16 + fq*4 + r;
        float v = acc[mi][ni][r];
        if (MODE==0)      ((float*)C1)[(size_t)row*ldc + col] = v;
        else if (MODE==1) ((u16*) C1)[(size_t)row*ldc + col] = f2bf(v);
        else {
          if (second) C2[(size_t)row*D_INNER + (col - D_INNER)] = f2bf(v);
          else        ((float*)C1)[(size_t)row*D_INNER + col] = v;
        }
      }
    }
  }
}

// ---------------------------------------------------------------------------
// f32 -> bf16 elementwise (n multiple of 1024)
// ---------------------------------------------------------------------------
__global__ __launch_bounds__(256)
void cvt_f32_bf16(const float* __restrict__ in, u16* __restrict__ out)
{
  size_t i = (size_t)blockIdx.x*256 + threadIdx.x;
  float4 v = ((const float4*)in)[i];
  ushort4 o;
  o.x=f2bf(v.x); o.y=f2bf(v.y); o.z=f2bf(v.z); o.w=f2bf(v.w);
  ((ushort4*)out)[i] = o;
}

// ---------------------------------------------------------------------------
// f32 [R][C] -> bf16 [C][R] transpose+convert, 64x64 tiles, 256 threads.
// ---------------------------------------------------------------------------
__global__ __launch_bounds__(256)
void transpose_cvt(const float* __restrict__ in, u16* __restrict__ out,
                   int R, int C)
{
  __shared__ float tile[64][65];
  const int bc = blockIdx.x*64, br = blockIdx.y*64;
  const int tx = threadIdx.x & 63, ty = threadIdx.x >> 6;
  #pragma unroll
  for (int i=0;i<16;i++){
    int r = ty + i*4;
    tile[r][tx] = in[(size_t)(br+r)*C + bc+tx];
  }
  __syncthreads();
  #pragma unroll
  for (int i=0;i<16;i++){
    int r = ty + i*4;
    out[(size_t)(bc+r)*R + br+tx] = f2bf(tile[tx][r]);
  }
}

// ---------------------------------------------------------------------------
// f32 tiled GEMM (small shapes): C[M,N] = A[M,K] @ B[K,N]
// EPI: 0 plain, 1 softplus(acc + bias[col]).
// ---------------------------------------------------------------------------
template<int BM,int BN,int BK,int TM,int TN,int EPI>
__global__ __launch_bounds__((BM/TM)*(BN/TN))
void sgemm(int K,
           const float* __restrict__ A,int lda,
           const float* __restrict__ B,int ldb,
           float* __restrict__ C,int ldc,
           const float* __restrict__ bias)
{
  __shared__ float As[BK][BM];
  __shared__ float Bs[BK][BN];
  const int tid  = threadIdx.x;
  const int brow = blockIdx.y, bcol = blockIdx.x;
  const int tcol = tid % (BN/TN);
  const int trow = tid / (BN/TN);

  const float* Ag = A + (size_t)brow*BM*lda;
  const float* Bg = B + (size_t)bcol*BN;

  const int arow = tid / (BK/4);
  const int acol = (tid % (BK/4))*4;
  const int brw  = tid / (BN/4);
  const int bcv  = (tid % (BN/4))*4;

  float acc[TM][TN] = {};

  for (int k0=0; k0<K; k0+=BK){
    float4 av = *(const float4*)(Ag + (size_t)arow*lda + k0 + acol);
    float4 bv = *(const float4*)(Bg + (size_t)(k0+brw)*ldb + bcv);
    __syncthreads();
    As[acol+0][arow]=av.x; As[acol+1][arow]=av.y;
    As[acol+2][arow]=av.z; As[acol+3][arow]=av.w;
    *(float4*)&Bs[brw][bcv] = bv;
    __syncthreads();
    #pragma unroll
    for (int kk=0;kk<BK;kk++){
      float ra[TM], rb[TN];
      #pragma unroll
      for (int m=0;m<TM;m++) ra[m]=As[kk][trow*TM+m];
      #pragma unroll
      for (int n=0;n<TN;n++) rb[n]=Bs[kk][tcol*TN+n];
      #pragma unroll
      for (int m=0;m<TM;m++)
        #pragma unroll
        for (int n=0;n<TN;n++)
          acc[m][n] += ra[m]*rb[n];
    }
  }

  #pragma unroll
  for (int m=0;m<TM;m++){
    int row = brow*BM + trow*TM + m;
    #pragma unroll
    for (int n=0;n<TN;n++){
      int col = bcol*BN + tcol*TN + n;
      float v = acc[m][n];
      if (EPI==1){
        v += bias[col];
        v = (v > 20.f) ? v : log1pf(__expf(v));
      }
      C[(size_t)row*ldc + col] = v;
    }
  }
}

// ---------------------------------------------------------------------------
// Depthwise causal conv (K=4) + bias + SiLU. xi_raw (f32, ld 2048) -> xi_post.
// ---------------------------------------------------------------------------
__global__ __launch_bounds__(256)
void conv_silu_kernel(const float* __restrict__ xi_raw,
                      const float* __restrict__ conv_w,
                      const float* __restrict__ conv_b,
                      float* __restrict__ xi_post)
{
  size_t idx = (size_t)blockIdx.x*256 + threadIdx.x;   // over NTOK*D_INNER
  int d = (int)(idx % D_INNER);
  size_t bt = idx / D_INNER;
  int t = (int)(bt % SEQ);
  size_t b = bt / SEQ;
  const float* xi = xi_raw + b*(size_t)SEQ*D_INNER;
  float accv = conv_b[d];
  #pragma unroll
  for (int k=0;k<D_CONV;k++){
    int tt = t + k - (D_CONV-1);
    if (tt >= 0) accv += xi[(size_t)tt*D_INNER + d] * conv_w[d*D_CONV + k];
  }
  xi_post[idx] = accv * sigmoidf_(accv);
}

// ---------------------------------------------------------------------------
// Chunked selective scan, pass 1: lane = channel, h[32] in registers.
// ---------------------------------------------------------------------------
__global__ __launch_bounds__(256)
void scan_part1(const float* __restrict__ dbc,     // (NTOK,128)
                const float* __restrict__ delta,   // (NTOK,D_INNER)
                const float* __restrict__ u,       // (NTOK,D_INNER)
                const float* __restrict__ A_log,   // (D_INNER,32)
                float* __restrict__ q,             // (B,NC,D_INNER,32)
                float* __restrict__ sumdl_buf)     // (B,NC,D_INNER)
{
  const int ndg  = D_INNER/256;                 // 8
  const int dgrp = blockIdx.x % ndg;
  const int c    = (blockIdx.x / ndg) % NC;
  const int b    =  blockIdx.x / (ndg*NC);
  const int d    = dgrp*256 + threadIdx.x;

  float A[D_STATE];
  #pragma unroll
  for (int g=0; g<8; ++g){
    float4 al = *(const float4*)(A_log + (size_t)d*D_STATE + 4*g);
    A[4*g+0] = -__expf(al.x); A[4*g+1] = -__expf(al.y);
    A[4*g+2] = -__expf(al.z); A[4*g+3] = -__expf(al.w);
  }

  const size_t tok0 = (size_t)b*SEQ + (size_t)c*CL;
  const float* dptr = delta + tok0*D_INNER + d;
  const float* uptr = u     + tok0*D_INNER + d;
  const float* dbcp = dbc   + tok0*DBC_N;

  float h[D_STATE] = {};
  float sumdl = 0.f;

  for (int t=0; t<CL; ++t){
    float dl = dptr[(size_t)t*D_INNER];
    float uu = uptr[(size_t)t*D_INNER];
    sumdl += dl;
    float w = dl*uu;
    const float4* B4 = (const float4*)(dbcp + (size_t)t*DBC_N + DT_RANK);
    #pragma unroll
    for (int g=0; g<8; ++g){
      float4 Bv = B4[g];
      h[4*g+0] = __expf(dl*A[4*g+0])*h[4*g+0] + w*Bv.x;
      h[4*g+1] = __expf(dl*A[4*g+1])*h[4*g+1] + w*Bv.y;
      h[4*g+2] = __expf(dl*A[4*g+2])*h[4*g+2] + w*Bv.z;
      h[4*g+3] = __expf(dl*A[4*g+3])*h[4*g+3] + w*Bv.w;
    }
  }

  float* qp = q + (((size_t)b*NC + c)*D_INNER + d)*D_STATE;
  #pragma unroll
  for (int g=0; g<8; ++g)
    ((float4*)qp)[g] = make_float4(h[4*g+0],h[4*g+1],h[4*g+2],h[4*g+3]);
  sumdl_buf[((size_t)b*NC + c)*D_INNER + d] = sumdl;
}

// ---------------------------------------------------------------------------
// Pass 2: sequential combine across chunks, in-place on q.
// ---------------------------------------------------------------------------
__global__ __launch_bounds__(256)
void scan_combine(float* __restrict__ q,
                  const float* __restrict__ sumdl_buf,
                  const float* __restrict__ A_log)
{
  size_t idx = (size_t)blockIdx.x*256 + threadIdx.x;   // over B*D_INNER*32
  int s = (int)(idx % D_STATE);
  size_t dd = idx / D_STATE;
  int d = (int)(dd % D_INNER);
  int b = (int)(dd / D_INNER);

  const float As = -__expf(A_log[(size_t)d*D_STATE + s]);
  float H = 0.f;
  for (int c=0; c<NC; ++c){
    size_t off = (((size_t)b*NC + c)*D_INNER + d)*D_STATE + s;
    float tmp = q[off];          // chunk-local end state
    q[off] = H;                  // h_in for chunk c
    H = __expf(As * sumdl_buf[((size_t)b*NC + c)*D_INNER + d]) * H + tmp;
  }
}

// ---------------------------------------------------------------------------
// Pass 3: re-run recurrence from h_in; y = sum_s h*C, fused D-skip + z-gate.
// z bf16 read, y bf16 written IN-PLACE (same slot, same thread -> race-free).
// ---------------------------------------------------------------------------
__global__ __launch_bounds__(256)
void scan_part2(const float* __restrict__ dbc,     // (NTOK,128)
                const float* __restrict__ delta,   // (NTOK,D_INNER)
                const float* __restrict__ u,
                u16*         __restrict__ zy,      // in: z bf16, out: y bf16
                const float* __restrict__ q,       // h_in per chunk
                const float* __restrict__ A_log,
                const float* __restrict__ Dp)
{
  const int ndg  = D_INNER/256;
  const int dgrp = blockIdx.x % ndg;
  const int c    = (blockIdx.x / ndg) % NC;
  const int b    =  blockIdx.x / (ndg*NC);
  const int d    = dgrp*256 + threadIdx.x;

  float A[D_STATE];
  #pragma unroll
  for (int g=0; g<8; ++g){
    float4 al = *(const float4*)(A_log + (size_t)d*D_STATE + 4*g);
    A[4*g+0] = -__expf(al.x); A[4*g+1] = -__expf(al.y);
    A[4*g+2] = -__expf(al.z); A[4*g+3] = -__expf(al.w);
  }
  float h[D_STATE];
  const float* qp = q + (((size_t)b*NC + c)*D_INNER + d)*D_STATE;
  #pragma unroll
  for (int g=0; g<8; ++g){
    float4 hv = ((const float4*)qp)[g];
    h[4*g+0]=hv.x; h[4*g+1]=hv.y; h[4*g+2]=hv.z; h[4*g+3]=hv.w;
  }
  const float Dd = Dp[d];

  const size_t tok0 = (size_t)b*SEQ + (size_t)c*CL;
  const float* dptr = delta + tok0*D_INNER + d;
  const float* uptr = u     + tok0*D_INNER + d;
  u16*         zp   = zy    + tok0*D_INNER + d;
  const float* dbcp = dbc   + tok0*DBC_N;

  for (int t=0; t<CL; ++t){
    float dl = dptr[(size_t)t*D_INNER];
    float uu = uptr[(size_t)t*D_INNER];
    float zz = bf2f(zp[(size_t)t*D_INNER]);
    float w  = dl*uu;
    const float4* B4 = (const float4*)(dbcp + (size_t)t*DBC_N + DT_RANK);
    const float4* C4 = B4 + 8;
    float y = 0.f;
    #pragma unroll
    for (int g=0; g<8; ++g){
      float4 Bv = B4[g];
      float4 Cv = C4[g];
      h[4*g+0] = __expf(dl*A[4*g+0])*h[4*g+0] + w*Bv.x;  y += h[4*g+0]*Cv.x;
      h[4*g+1] = __expf(dl*A[4*g+1])*h[4*g+1] + w*Bv.y;  y += h[4*g+1]*Cv.y;
      h[4*g+2] = __expf(dl*A[4*g+2])*h[4*g+2] + w*Bv.z;  y += h[4*g+2]*Cv.z;
      h[4*g+3] = __expf(dl*A[4*g+3])*h[4*g+3] + w*Bv.w;  y += h[4*g+3]*Cv.w;
    }
    zp[(size_t)t*D_INNER] = f2bf((y + uu*Dd) * (zz * sigmoidf_(zz)));
  }
}

// ---------------------------------------------------------------------------
// LayerNorm over last dim (1024): read f32 pre-LN, write f32 output.
// ---------------------------------------------------------------------------
__global__ __launch_bounds__(256)
void ln_kernel(const float* __restrict__ in,
               float* __restrict__ out,
               const float* __restrict__ gamma,
               const float* __restrict__ beta)
{
  const int row = blockIdx.x;
  const float* p = in + (size_t)row*D_MODEL;
  float* q = out + (size_t)row*D_MODEL;
  float v[4]; float s=0.f, ss=0.f;
  #pragma unroll
  for (int i=0;i<4;i++){
    float x = p[i*256 + threadIdx.x];
    v[i]=x; s+=x; ss+=x*x;
  }
  #pragma unroll
  for (int off=32; off; off>>=1){
    s  += __shfl_xor(s,  off, 64);
    ss += __shfl_xor(ss, off, 64);
  }
  __shared__ float sw[4], ssw[4];
  const int wid = threadIdx.x >> 6;
  if ((threadIdx.x & 63) == 0){ sw[wid]=s; ssw[wid]=ss; }
  __syncthreads();
  s  = sw[0]+sw[1]+sw[2]+sw[3];
  ss = ssw[0]+ssw[1]+ssw[2]+ssw[3];
  const float mu  = s * (1.f/D_MODEL);
  const float var = ss * (1.f/D_MODEL) - mu*mu;
  const float inv = rsqrtf(var + 1e-5f);
  #pragma unroll
  for (int i=0;i<4;i++){
    int col = i*256 + threadIdx.x;
    q[col] = (v[i]-mu)*inv*gamma[col] + beta[col];
  }
}

// ---------------------------------------------------------------------------
extern "C" void kernel_launch(void* const* d_in, const int* in_sizes, int n_in,
                              void* d_out, int out_size, void* d_ws, size_t ws_size,
                              hipStream_t stream)
{
  const float* x          = (const float*)d_in[0];   // (4,2048,1024) f32
  const float* in_proj_w  = (const float*)d_in[1];   // (1024,4096)
  const float* conv_w     = (const float*)d_in[2];   // (2048,4)
  const float* conv_b     = (const float*)d_in[3];   // (2048,)
  const float* x_proj_w   = (const float*)d_in[4];   // (2048,128)
  const float* dt_proj_w  = (const float*)d_in[5];   // (64,2048)
  const float* dt_proj_b  = (const float*)d_in[6];   // (2048,)
  const float* A_log      = (const float*)d_in[7];   // (2048,32)
  const float* Dp         = (const float*)d_in[8];   // (2048,)
  const float* out_proj_w = (const float*)d_in[9];   // (2048,1024)
  const float* ln_gamma   = (const float*)d_in[10];  // (1024,)
  const float* ln_beta    = (const float*)d_in[11];  // (1024,)
  float* out = (float*)d_out;                        // (4,2048,1024) f32 OUTPUT

  // workspace (MiB offsets). Evidence: writes ending at 192 MiB ran (R8);
  // first byte at 256 MiB faulted (R3) -> ws_size = 256 MiB. Stay < 242 MiB.
  //   @0    xi_raw f32 64M -> delta f32 -> preln f32
  //   @64   xi_post f32 64M
  //   @128  z bf16 32M -> y bf16 (in-place)
  //   @160  x_bf 16M (prep only) / dbc f32 4M (after x_bf dead)
  //   @164  qbuf f32 64M  [164,228)
  //   @228  sumdl f32 2M  [228,230)
  //   @230  w_inT bf16 8M [230,238)
  //   @238  w_outT bf16 4M [238,242)
  char* ws = (char*)d_ws;
  float* xi_raw  = (float*)(ws + 0);
  float* deltab  = (float*)(ws + 0);
  float* preln   = (float*)(ws + 0);
  float* xi_post = (float*)(ws + (size_t) 67108864);
  u16*   zybuf   = (u16*)  (ws + (size_t)134217728);
  u16*   x_bf    = (u16*)  (ws + (size_t)167772160);
  float* dbc     = (float*)(ws + (size_t)167772160);
  float* qbuf    = (float*)(ws + (size_t)171966464);
  float* sumdl   = (float*)(ws + (size_t)239075328);
  u16*   w_inT   = (u16*)  (ws + (size_t)241172480);
  u16*   w_outT  = (u16*)  (ws + (size_t)249561088);

  // 0) dtype prep: x -> bf16; weights -> bf16 transposed [N][K]
  cvt_f32_bf16<<<(NTOK*(size_t)D_MODEL)/1024, 256, 0, stream>>>(x, x_bf);
  { dim3 g(4096/64, 1024/64); transpose_cvt<<<g,256,0,stream>>>(in_proj_w,  w_inT,  1024, 4096); }
  { dim3 g(1024/64, 2048/64); transpose_cvt<<<g,256,0,stream>>>(out_proj_w, w_outT, 2048, 1024); }

  // 1) merged in_proj: [xi | z] = x @ in_proj_w  (MFMA, split epilogue)
  {
    dim3 grid(2*D_INNER/128, NTOK/128);
    mfma_gemm<2><<<grid,256,0,stream>>>(D_MODEL,
        x_bf, D_MODEL, w_inT, D_MODEL, xi_raw, 0, zybuf);
  }
  // 2) xi_post = silu(conv(xi_raw) + conv_b)
  conv_silu_kernel<<<(NTOK*(size_t)D_INNER)/256,256,0,stream>>>(xi_raw, conv_w, conv_b, xi_post);

  // 3) dbc = xi_post @ x_proj_w            M=8192 N=128 K=2048 (f32)
  {
    dim3 grid(DBC_N/64, NTOK/64);
    sgemm<64,64,16,4,4,0><<<grid,256,0,stream>>>(D_INNER,
        xi_post,D_INNER, x_proj_w,DBC_N, dbc,DBC_N, nullptr);
  }
  // 4) delta = softplus(dbc[:, :64] @ dt_proj_w + b)  M=8192 N=2048 K=64 -> @0
  {
    dim3 grid(D_INNER/64, NTOK/64);
    sgemm<64,64,16,4,4,1><<<grid,256,0,stream>>>(DT_RANK,
        dbc,DBC_N, dt_proj_w,D_INNER, deltab,D_INNER, dt_proj_b);
  }
  // 5) chunked scan (NC=64); part2 writes y bf16 in-place over z
  {
    dim3 grid1((D_INNER/256)*NC*BATCH);           // 2048 blocks
    scan_part1<<<grid1,256,0,stream>>>(dbc, deltab, xi_post, A_log, qbuf, sumdl);
    scan_combine<<<(BATCH*(size_t)D_INNER*D_STATE)/256,256,0,stream>>>(qbuf, sumdl, A_log);
    scan_part2<<<grid1,256,0,stream>>>(dbc, deltab, xi_post, zybuf, qbuf, A_log, Dp);
  }
  // 6) preln = y @ out_proj_w              (MFMA, f32 out) -> @0
  {
    dim3 grid(D_MODEL/128, NTOK/128);
    mfma_gemm<0><<<grid,256,0,stream>>>(D_INNER,
        zybuf, D_INNER, w_outT, D_INNER, preln, D_MODEL, nullptr);
  }
  // 7) LayerNorm: preln f32 -> out f32
  ln_kernel<<<NTOK,256,0,stream>>>(preln, out, ln_gamma, ln_beta);
}

// Round 10
// 768.264 us; speedup vs baseline: 5.6314x; 1.0468x over previous
//
#include <hip/hip_runtime.h>
#include <math.h>

#define D_MODEL 1024
#define D_STATE 32
#define D_CONV  4
#define D_INNER 2048
#define DT_RANK 64
#define BATCH   4
#define SEQ     2048
#define NTOK    (BATCH*SEQ)            // 8192 rows
#define DBC_N   (DT_RANK + 2*D_STATE)  // 128
#define NC      64                     // scan chunks
#define CL      (SEQ/NC)               // 32 steps per chunk
#define LDK     40                     // padded LDS row (elems) for MFMA tiles
#define KSPLIT  8                      // split-K factor for dbc GEMM

typedef unsigned short u16;
typedef short bf16x8 __attribute__((ext_vector_type(8)));
typedef float f32x4  __attribute__((ext_vector_type(4)));
typedef u16   u16x8  __attribute__((ext_vector_type(8)));

__device__ __forceinline__ float bf2f(u16 u){
  return __uint_as_float(((unsigned)u) << 16);
}
__device__ __forceinline__ u16 f2bf(float f){   // round-to-nearest-even
  unsigned u = __float_as_uint(f);
  return (u16)((u + 0x7fffu + ((u >> 16) & 1u)) >> 16);
}
__device__ __forceinline__ float sigmoidf_(float x){ return 1.f/(1.f+__expf(-x)); }

// ---------------------------------------------------------------------------
// bf16 MFMA GEMM: C = A[M,K] @ W[K,N], A bf16 row-major [M][K], B = weight
// PRE-TRANSPOSED bf16 [N][K]. 128x128 tile, BK=32, 4 waves of 64x64.
// MODE 0: f32 store. MODE 2 (split in_proj): col<D_INNER -> f32 C1;
// col>=D_INNER -> bf16 C2@col-2048.
// ---------------------------------------------------------------------------
template<int MODE>
__global__ __launch_bounds__(256)
void mfma_gemm(int K,
               const u16* __restrict__ A, int lda,
               const u16* __restrict__ B, int ldb,   // [N][K]
               void* __restrict__ C1, int ldc,
               u16*  __restrict__ C2)
{
  __shared__ u16 As[128*LDK];
  __shared__ u16 Bs[128*LDK];
  const int tid  = threadIdx.x;
  const int lane = tid & 63;
  const int wave = tid >> 6;
  const int wm = (wave>>1)*64, wn = (wave&1)*64;
  const int m0 = blockIdx.y*128, n0 = blockIdx.x*128;

  const int sr = tid >> 2;          // 0..63
  const int sc = (tid & 3) * 8;     // elem offset within 32-wide K slice

  const u16* Ag = A + (size_t)m0*lda;
  const u16* Bg = B + (size_t)n0*ldb;

  const int fr = lane & 15;         // fragment row within 16
  const int fq = lane >> 4;         // quad: k-chunk of 8
  f32x4 acc[4][4] = {};

  for (int k0=0; k0<K; k0+=32){
    u16x8 a0 = *(const u16x8*)(Ag + (size_t) sr    *lda + k0 + sc);
    u16x8 a1 = *(const u16x8*)(Ag + (size_t)(sr+64)*lda + k0 + sc);
    u16x8 b0 = *(const u16x8*)(Bg + (size_t) sr    *ldb + k0 + sc);
    u16x8 b1 = *(const u16x8*)(Bg + (size_t)(sr+64)*ldb + k0 + sc);
    __syncthreads();
    *(u16x8*)&As[ sr    *LDK + sc] = a0;
    *(u16x8*)&As[(sr+64)*LDK + sc] = a1;
    *(u16x8*)&Bs[ sr    *LDK + sc] = b0;
    *(u16x8*)&Bs[(sr+64)*LDK + sc] = b1;
    __syncthreads();

    bf16x8 af[4], bfr[4];
    #pragma unroll
    for (int i=0;i<4;i++){
      af[i]  = *(const bf16x8*)&As[(wm + i*16 + fr)*LDK + fq*8];
      bfr[i] = *(const bf16x8*)&Bs[(wn + i*16 + fr)*LDK + fq*8];
    }
    #pragma unroll
    for (int mi=0;mi<4;mi++)
      #pragma unroll
      for (int ni=0;ni<4;ni++)
        acc[mi][ni] = __builtin_amdgcn_mfma_f32_16x16x32_bf16(
            af[mi], bfr[ni], acc[mi][ni], 0, 0, 0);
  }

  // C/D layout: row = fq*4 + r, col = fr  (m89-verified)
  const bool second = (MODE==2) && (n0 >= D_INNER);   // block-uniform
  #pragma unroll
  for (int mi=0;mi<4;mi++){
    #pragma unroll
    for (int ni=0;ni<4;ni++){
      int col = n0 + wn + ni*16 + fr;
      #pragma unroll
      for (int r=0;r<4;r++){
        int row = m0 + wm + mi*16 + fq*4 + r;
        float v = acc[mi][ni][r];
        if (MODE==0)      ((float*)C1)[(size_t)row*ldc + col] = v;
        else {
          if (second) C2[(size_t)row*D_INNER + (col - D_INNER)] = f2bf(v);
          else        ((float*)C1)[(size_t)row*D_INNER + col] = v;
        }
      }
    }
  }
}

// ---------------------------------------------------------------------------
// f32 -> bf16 elementwise (n multiple of 1024)
// ---------------------------------------------------------------------------
__global__ __launch_bounds__(256)
void cvt_f32_bf16(const float* __restrict__ in, u16* __restrict__ out)
{
  size_t i = (size_t)blockIdx.x*256 + threadIdx.x;
  float4 v = ((const float4*)in)[i];
  ushort4 o;
  o.x=f2bf(v.x); o.y=f2bf(v.y); o.z=f2bf(v.z); o.w=f2bf(v.w);
  ((ushort4*)out)[i] = o;
}

// ---------------------------------------------------------------------------
// f32 [R][C] -> bf16 [C][R] transpose+convert, 64x64 tiles, 256 threads.
// ---------------------------------------------------------------------------
__global__ __launch_bounds__(256)
void transpose_cvt(const float* __restrict__ in, u16* __restrict__ out,
                   int R, int C)
{
  __shared__ float tile[64][65];
  const int bc = blockIdx.x*64, br = blockIdx.y*64;
  const int tx = threadIdx.x & 63, ty = threadIdx.x >> 6;
  #pragma unroll
  for (int i=0;i<16;i++){
    int r = ty + i*4;
    tile[r][tx] = in[(size_t)(br+r)*C + bc+tx];
  }
  __syncthreads();
  #pragma unroll
  for (int i=0;i<16;i++){
    int r = ty + i*4;
    out[(size_t)(bc+r)*R + br+tx] = f2bf(tile[tx][r]);
  }
}

// ---------------------------------------------------------------------------
// f32 tiled GEMM: C[M,N] = A[M,K] @ B[K,N]
// EPI: 0 plain, 1 softplus(acc + bias[col]).
// ---------------------------------------------------------------------------
template<int BM,int BN,int BK,int TM,int TN,int EPI>
__global__ __launch_bounds__((BM/TM)*(BN/TN))
void sgemm(int K,
           const float* __restrict__ A,int lda,
           const float* __restrict__ B,int ldb,
           float* __restrict__ C,int ldc,
           const float* __restrict__ bias)
{
  __shared__ float As[BK][BM];
  __shared__ float Bs[BK][BN];
  const int tid  = threadIdx.x;
  const int brow = blockIdx.y, bcol = blockIdx.x;
  const int tcol = tid % (BN/TN);
  const int trow = tid / (BN/TN);

  const float* Ag = A + (size_t)brow*BM*lda;
  const float* Bg = B + (size_t)bcol*BN;

  const int arow = tid / (BK/4);
  const int acol = (tid % (BK/4))*4;
  const int brw  = tid / (BN/4);
  const int bcv  = (tid % (BN/4))*4;

  float acc[TM][TN] = {};

  for (int k0=0; k0<K; k0+=BK){
    float4 av = *(const float4*)(Ag + (size_t)arow*lda + k0 + acol);
    float4 bv = *(const float4*)(Bg + (size_t)(k0+brw)*ldb + bcv);
    __syncthreads();
    As[acol+0][arow]=av.x; As[acol+1][arow]=av.y;
    As[acol+2][arow]=av.z; As[acol+3][arow]=av.w;
    *(float4*)&Bs[brw][bcv] = bv;
    __syncthreads();
    #pragma unroll
    for (int kk=0;kk<BK;kk++){
      float ra[TM], rb[TN];
      #pragma unroll
      for (int m=0;m<TM;m++) ra[m]=As[kk][trow*TM+m];
      #pragma unroll
      for (int n=0;n<TN;n++) rb[n]=Bs[kk][tcol*TN+n];
      #pragma unroll
      for (int m=0;m<TM;m++)
        #pragma unroll
        for (int n=0;n<TN;n++)
          acc[m][n] += ra[m]*rb[n];
    }
  }

  #pragma unroll
  for (int m=0;m<TM;m++){
    int row = brow*BM + trow*TM + m;
    #pragma unroll
    for (int n=0;n<TN;n++){
      int col = bcol*BN + tcol*TN + n;
      float v = acc[m][n];
      if (EPI==1){
        v += bias[col];
        v = (v > 20.f) ? v : log1pf(__expf(v));
      }
      C[(size_t)row*ldc + col] = v;
    }
  }
}

// ---------------------------------------------------------------------------
// Split-K f32 GEMM (dbc): partial[z] = A[:, zKc:(z+1)Kc] @ B[zKc:, :]
// 64x64 tile, BK=16. grid = (N/64, M/64, KSPLIT). Kc = K/KSPLIT.
// ---------------------------------------------------------------------------
__global__ __launch_bounds__(256)
void sgemm_pk(int K,
              const float* __restrict__ A,int lda,
              const float* __restrict__ B,int ldb,
              float* __restrict__ part)          // (KSPLIT, NTOK, DBC_N)
{
  const int BM=64, BN=64, BK=16, TM=4, TN=4;
  __shared__ float As[BK][BM];
  __shared__ float Bs[BK][BN];
  const int tid  = threadIdx.x;
  const int brow = blockIdx.y, bcol = blockIdx.x, kz = blockIdx.z;
  const int Kc   = K / KSPLIT;
  const int tcol = tid % (BN/TN);
  const int trow = tid / (BN/TN);

  const float* Ag = A + (size_t)brow*BM*lda + (size_t)kz*Kc;
  const float* Bg = B + (size_t)kz*Kc*ldb + (size_t)bcol*BN;

  const int arow = tid / (BK/4);
  const int acol = (tid % (BK/4))*4;
  const int brw  = tid / (BN/4);
  const int bcv  = (tid % (BN/4))*4;

  float acc[TM][TN] = {};

  for (int k0=0; k0<Kc; k0+=BK){
    float4 av = *(const float4*)(Ag + (size_t)arow*lda + k0 + acol);
    float4 bv = *(const float4*)(Bg + (size_t)(k0+brw)*ldb + bcv);
    __syncthreads();
    As[acol+0][arow]=av.x; As[acol+1][arow]=av.y;
    As[acol+2][arow]=av.z; As[acol+3][arow]=av.w;
    *(float4*)&Bs[brw][bcv] = bv;
    __syncthreads();
    #pragma unroll
    for (int kk=0;kk<BK;kk++){
      float ra[TM], rb[TN];
      #pragma unroll
      for (int m=0;m<TM;m++) ra[m]=As[kk][trow*TM+m];
      #pragma unroll
      for (int n=0;n<TN;n++) rb[n]=Bs[kk][tcol*TN+n];
      #pragma unroll
      for (int m=0;m<TM;m++)
        #pragma unroll
        for (int n=0;n<TN;n++)
          acc[m][n] += ra[m]*rb[n];
    }
  }

  float* P = part + (size_t)kz*NTOK*DBC_N;
  #pragma unroll
  for (int m=0;m<TM;m++){
    int row = brow*BM + trow*TM + m;
    #pragma unroll
    for (int n=0;n<TN;n++){
      int col = bcol*BN + tcol*TN + n;
      P[(size_t)row*DBC_N + col] = acc[m][n];
    }
  }
}

// reduce KSPLIT partials into dbc (float4-vectorized over NTOK*DBC_N)
__global__ __launch_bounds__(256)
void reduce_pk(const float* __restrict__ part, float* __restrict__ dbc)
{
  size_t i = (size_t)blockIdx.x*256 + threadIdx.x;   // float4 index
  const size_t stride4 = (size_t)NTOK*DBC_N/4;
  float4 s = ((const float4*)part)[i];
  #pragma unroll
  for (int z=1; z<KSPLIT; ++z){
    float4 v = ((const float4*)part)[z*stride4 + i];
    s.x+=v.x; s.y+=v.y; s.z+=v.z; s.w+=v.w;
  }
  ((float4*)dbc)[i] = s;
}

// ---------------------------------------------------------------------------
// Depthwise causal conv (K=4) + bias + SiLU. xi_raw (f32, ld 2048) -> xi_post.
// ---------------------------------------------------------------------------
__global__ __launch_bounds__(256)
void conv_silu_kernel(const float* __restrict__ xi_raw,
                      const float* __restrict__ conv_w,
                      const float* __restrict__ conv_b,
                      float* __restrict__ xi_post)
{
  size_t idx = (size_t)blockIdx.x*256 + threadIdx.x;   // over NTOK*D_INNER
  int d = (int)(idx % D_INNER);
  size_t bt = idx / D_INNER;
  int t = (int)(bt % SEQ);
  size_t b = bt / SEQ;
  const float* xi = xi_raw + b*(size_t)SEQ*D_INNER;
  float accv = conv_b[d];
  #pragma unroll
  for (int k=0;k<D_CONV;k++){
    int tt = t + k - (D_CONV-1);
    if (tt >= 0) accv += xi[(size_t)tt*D_INNER + d] * conv_w[d*D_CONV + k];
  }
  xi_post[idx] = accv * sigmoidf_(accv);
}

// ---------------------------------------------------------------------------
// Chunked selective scan, pass 1: lane = channel, h[32] in registers.
// ---------------------------------------------------------------------------
__global__ __launch_bounds__(256)
void scan_part1(const float* __restrict__ dbc,     // (NTOK,128)
                const float* __restrict__ delta,   // (NTOK,D_INNER)
                const float* __restrict__ u,       // (NTOK,D_INNER)
                const float* __restrict__ A_log,   // (D_INNER,32)
                float* __restrict__ q,             // (B,NC,D_INNER,32)
                float* __restrict__ sumdl_buf)     // (B,NC,D_INNER)
{
  const int ndg  = D_INNER/256;                 // 8
  const int dgrp = blockIdx.x % ndg;
  const int c    = (blockIdx.x / ndg) % NC;
  const int b    =  blockIdx.x / (ndg*NC);
  const int d    = dgrp*256 + threadIdx.x;

  float A[D_STATE];
  #pragma unroll
  for (int g=0; g<8; ++g){
    float4 al = *(const float4*)(A_log + (size_t)d*D_STATE + 4*g);
    A[4*g+0] = -__expf(al.x); A[4*g+1] = -__expf(al.y);
    A[4*g+2] = -__expf(al.z); A[4*g+3] = -__expf(al.w);
  }

  const size_t tok0 = (size_t)b*SEQ + (size_t)c*CL;
  const float* dptr = delta + tok0*D_INNER + d;
  const float* uptr = u     + tok0*D_INNER + d;
  const float* dbcp = dbc   + tok0*DBC_N;

  float h[D_STATE] = {};
  float sumdl = 0.f;

  for (int t=0; t<CL; ++t){
    float dl = dptr[(size_t)t*D_INNER];
    float uu = uptr[(size_t)t*D_INNER];
    sumdl += dl;
    float w = dl*uu;
    const float4* B4 = (const float4*)(dbcp + (size_t)t*DBC_N + DT_RANK);
    #pragma unroll
    for (int g=0; g<8; ++g){
      float4 Bv = B4[g];
      h[4*g+0] = __expf(dl*A[4*g+0])*h[4*g+0] + w*Bv.x;
      h[4*g+1] = __expf(dl*A[4*g+1])*h[4*g+1] + w*Bv.y;
      h[4*g+2] = __expf(dl*A[4*g+2])*h[4*g+2] + w*Bv.z;
      h[4*g+3] = __expf(dl*A[4*g+3])*h[4*g+3] + w*Bv.w;
    }
  }

  float* qp = q + (((size_t)b*NC + c)*D_INNER + d)*D_STATE;
  #pragma unroll
  for (int g=0; g<8; ++g)
    ((float4*)qp)[g] = make_float4(h[4*g+0],h[4*g+1],h[4*g+2],h[4*g+3]);
  sumdl_buf[((size_t)b*NC + c)*D_INNER + d] = sumdl;
}

// ---------------------------------------------------------------------------
// Pass 2: sequential combine across chunks, in-place on q.
// ---------------------------------------------------------------------------
__global__ __launch_bounds__(256)
void scan_combine(float* __restrict__ q,
                  const float* __restrict__ sumdl_buf,
                  const float* __restrict__ A_log)
{
  size_t idx = (size_t)blockIdx.x*256 + threadIdx.x;   // over B*D_INNER*32
  int s = (int)(idx % D_STATE);
  size_t dd = idx / D_STATE;
  int d = (int)(dd % D_INNER);
  int b = (int)(dd / D_INNER);

  const float As = -__expf(A_log[(size_t)d*D_STATE + s]);
  float H = 0.f;
  for (int c=0; c<NC; ++c){
    size_t off = (((size_t)b*NC + c)*D_INNER + d)*D_STATE + s;
    float tmp = q[off];          // chunk-local end state
    q[off] = H;                  // h_in for chunk c
    H = __expf(As * sumdl_buf[((size_t)b*NC + c)*D_INNER + d]) * H + tmp;
  }
}

// ---------------------------------------------------------------------------
// Pass 3: re-run recurrence from h_in; y = sum_s h*C, fused D-skip + z-gate.
// z bf16 read, y bf16 written IN-PLACE (same slot, same thread -> race-free).
// ---------------------------------------------------------------------------
__global__ __launch_bounds__(256)
void scan_part2(const float* __restrict__ dbc,     // (NTOK,128)
                const float* __restrict__ delta,   // (NTOK,D_INNER)
                const float* __restrict__ u,
                u16*         __restrict__ zy,      // in: z bf16, out: y bf16
                const float* __restrict__ q,       // h_in per chunk
                const float* __restrict__ A_log,
                const float* __restrict__ Dp)
{
  const int ndg  = D_INNER/256;
  const int dgrp = blockIdx.x % ndg;
  const int c    = (blockIdx.x / ndg) % NC;
  const int b    =  blockIdx.x / (ndg*NC);
  const int d    = dgrp*256 + threadIdx.x;

  float A[D_STATE];
  #pragma unroll
  for (int g=0; g<8; ++g){
    float4 al = *(const float4*)(A_log + (size_t)d*D_STATE + 4*g);
    A[4*g+0] = -__expf(al.x); A[4*g+1] = -__expf(al.y);
    A[4*g+2] = -__expf(al.z); A[4*g+3] = -__expf(al.w);
  }
  float h[D_STATE];
  const float* qp = q + (((size_t)b*NC + c)*D_INNER + d)*D_STATE;
  #pragma unroll
  for (int g=0; g<8; ++g){
    float4 hv = ((const float4*)qp)[g];
    h[4*g+0]=hv.x; h[4*g+1]=hv.y; h[4*g+2]=hv.z; h[4*g+3]=hv.w;
  }
  const float Dd = Dp[d];

  const size_t tok0 = (size_t)b*SEQ + (size_t)c*CL;
  const float* dptr = delta + tok0*D_INNER + d;
  const float* uptr = u     + tok0*D_INNER + d;
  u16*         zp   = zy    + tok0*D_INNER + d;
  const float* dbcp = dbc   + tok0*DBC_N;

  for (int t=0; t<CL; ++t){
    float dl = dptr[(size_t)t*D_INNER];
    float uu = uptr[(size_t)t*D_INNER];
    float zz = bf2f(zp[(size_t)t*D_INNER]);
    float w  = dl*uu;
    const float4* B4 = (const float4*)(dbcp + (size_t)t*DBC_N + DT_RANK);
    const float4* C4 = B4 + 8;
    float y = 0.f;
    #pragma unroll
    for (int g=0; g<8; ++g){
      float4 Bv = B4[g];
      float4 Cv = C4[g];
      h[4*g+0] = __expf(dl*A[4*g+0])*h[4*g+0] + w*Bv.x;  y += h[4*g+0]*Cv.x;
      h[4*g+1] = __expf(dl*A[4*g+1])*h[4*g+1] + w*Bv.y;  y += h[4*g+1]*Cv.y;
      h[4*g+2] = __expf(dl*A[4*g+2])*h[4*g+2] + w*Bv.z;  y += h[4*g+2]*Cv.z;
      h[4*g+3] = __expf(dl*A[4*g+3])*h[4*g+3] + w*Bv.w;  y += h[4*g+3]*Cv.w;
    }
    zp[(size_t)t*D_INNER] = f2bf((y + uu*Dd) * (zz * sigmoidf_(zz)));
  }
}

// ---------------------------------------------------------------------------
// LayerNorm over last dim (1024): read f32 pre-LN, write f32 output.
// ---------------------------------------------------------------------------
__global__ __launch_bounds__(256)
void ln_kernel(const float* __restrict__ in,
               float* __restrict__ out,
               const float* __restrict__ gamma,
               const float* __restrict__ beta)
{
  const int row = blockIdx.x;
  const float* p = in + (size_t)row*D_MODEL;
  float* q = out + (size_t)row*D_MODEL;
  float v[4]; float s=0.f, ss=0.f;
  #pragma unroll
  for (int i=0;i<4;i++){
    float x = p[i*256 + threadIdx.x];
    v[i]=x; s+=x; ss+=x*x;
  }
  #pragma unroll
  for (int off=32; off; off>>=1){
    s  += __shfl_xor(s,  off, 64);
    ss += __shfl_xor(ss, off, 64);
  }
  __shared__ float sw[4], ssw[4];
  const int wid = threadIdx.x >> 6;
  if ((threadIdx.x & 63) == 0){ sw[wid]=s; ssw[wid]=ss; }
  __syncthreads();
  s  = sw[0]+sw[1]+sw[2]+sw[3];
  ss = ssw[0]+ssw[1]+ssw[2]+ssw[3];
  const float mu  = s * (1.f/D_MODEL);
  const float var = ss * (1.f/D_MODEL) - mu*mu;
  const float inv = rsqrtf(var + 1e-5f);
  #pragma unroll
  for (int i=0;i<4;i++){
    int col = i*256 + threadIdx.x;
    q[col] = (v[i]-mu)*inv*gamma[col] + beta[col];
  }
}

// ---------------------------------------------------------------------------
extern "C" void kernel_launch(void* const* d_in, const int* in_sizes, int n_in,
                              void* d_out, int out_size, void* d_ws, size_t ws_size,
                              hipStream_t stream)
{
  const float* x          = (const float*)d_in[0];   // (4,2048,1024) f32
  const float* in_proj_w  = (const float*)d_in[1];   // (1024,4096)
  const float* conv_w     = (const float*)d_in[2];   // (2048,4)
  const float* conv_b     = (const float*)d_in[3];   // (2048,)
  const float* x_proj_w   = (const float*)d_in[4];   // (2048,128)
  const float* dt_proj_w  = (const float*)d_in[5];   // (64,2048)
  const float* dt_proj_b  = (const float*)d_in[6];   // (2048,)
  const float* A_log      = (const float*)d_in[7];   // (2048,32)
  const float* Dp         = (const float*)d_in[8];   // (2048,)
  const float* out_proj_w = (const float*)d_in[9];   // (2048,1024)
  const float* ln_gamma   = (const float*)d_in[10];  // (1024,)
  const float* ln_beta    = (const float*)d_in[11];  // (1024,)
  float* out = (float*)d_out;                        // (4,2048,1024) f32 OUTPUT

  // workspace (MiB offsets), ws_size = 256 MiB (R3 fault @256M; R9 used <242M):
  //   @0    xi_raw f32 64M -> pkpart f32 32M (dbc split-K) -> delta f32 -> preln
  //   @64   xi_post f32 64M
  //   @128  z bf16 32M -> y bf16 (in-place)
  //   @160  x_bf 16M (prep only) / dbc f32 4M (after x_bf dead)
  //   @164  qbuf f32 64M  [164,228)
  //   @228  sumdl f32 2M  [228,230)
  //   @230  w_inT bf16 8M [230,238)
  //   @238  w_outT bf16 4M [238,242)
  char* ws = (char*)d_ws;
  float* xi_raw  = (float*)(ws + 0);
  float* pkpart  = (float*)(ws + 0);
  float* deltab  = (float*)(ws + 0);
  float* preln   = (float*)(ws + 0);
  float* xi_post = (float*)(ws + (size_t) 67108864);
  u16*   zybuf   = (u16*)  (ws + (size_t)134217728);
  u16*   x_bf    = (u16*)  (ws + (size_t)167772160);
  float* dbc     = (float*)(ws + (size_t)167772160);
  float* qbuf    = (float*)(ws + (size_t)171966464);
  float* sumdl   = (float*)(ws + (size_t)239075328);
  u16*   w_inT   = (u16*)  (ws + (size_t)241172480);
  u16*   w_outT  = (u16*)  (ws + (size_t)249561088);

  // 0) dtype prep: x -> bf16; weights -> bf16 transposed [N][K]
  cvt_f32_bf16<<<(NTOK*(size_t)D_MODEL)/1024, 256, 0, stream>>>(x, x_bf);
  { dim3 g(4096/64, 1024/64); transpose_cvt<<<g,256,0,stream>>>(in_proj_w,  w_inT,  1024, 4096); }
  { dim3 g(1024/64, 2048/64); transpose_cvt<<<g,256,0,stream>>>(out_proj_w, w_outT, 2048, 1024); }

  // 1) merged in_proj: [xi | z] = x @ in_proj_w  (MFMA, split epilogue)
  {
    dim3 grid(2*D_INNER/128, NTOK/128);
    mfma_gemm<2><<<grid,256,0,stream>>>(D_MODEL,
        x_bf, D_MODEL, w_inT, D_MODEL, xi_raw, 0, zybuf);
  }
  // 2) xi_post = silu(conv(xi_raw) + conv_b)   (xi_raw dead after this)
  conv_silu_kernel<<<(NTOK*(size_t)D_INNER)/256,256,0,stream>>>(xi_raw, conv_w, conv_b, xi_post);

  // 3) dbc = xi_post @ x_proj_w   M=8192 N=128 K=2048 -- split-K over 8 for
  //    occupancy (R9: 256 blocks -> 11% occ, 22% VALU). Partials over dead
  //    xi_raw, then reduce into dbc.
  {
    dim3 grid(DBC_N/64, NTOK/64, KSPLIT);       // 2048 blocks
    sgemm_pk<<<grid,256,0,stream>>>(D_INNER,
        xi_post,D_INNER, x_proj_w,DBC_N, pkpart);
    reduce_pk<<<(NTOK*(size_t)DBC_N)/1024,256,0,stream>>>(pkpart, dbc);
  }
  // 4) delta = softplus(dbc[:, :64] @ dt_proj_w + b)  M=8192 N=2048 K=64 -> @0
  {
    dim3 grid(D_INNER/64, NTOK/64);
    sgemm<64,64,16,4,4,1><<<grid,256,0,stream>>>(DT_RANK,
        dbc,DBC_N, dt_proj_w,D_INNER, deltab,D_INNER, dt_proj_b);
  }
  // 5) chunked scan (NC=64); part2 writes y bf16 in-place over z
  {
    dim3 grid1((D_INNER/256)*NC*BATCH);           // 2048 blocks
    scan_part1<<<grid1,256,0,stream>>>(dbc, deltab, xi_post, A_log, qbuf, sumdl);
    scan_combine<<<(BATCH*(size_t)D_INNER*D_STATE)/256,256,0,stream>>>(qbuf, sumdl, A_log);
    scan_part2<<<grid1,256,0,stream>>>(dbc, deltab, xi_post, zybuf, qbuf, A_log, Dp);
  }
  // 6) preln = y @ out_proj_w              (MFMA, f32 out) -> @0
  {
    dim3 grid(D_MODEL/128, NTOK/128);
    mfma_gemm<0><<<grid,256,0,stream>>>(D_INNER,
        zybuf, D_INNER, w_outT, D_INNER, preln, D_MODEL, nullptr);
  }
  // 7) LayerNorm: preln f32 -> out f32
  ln_kernel<<<NTOK,256,0,stream>>>(preln, out, ln_gamma, ln_beta);
}